// Round 1
// baseline (1011.617 us; speedup 1.0000x reference)
//
#include <hip/hip_runtime.h>
#include <hip/hip_bf16.h>
#include <stdint.h>

#define DEVI __device__ __forceinline__

typedef __attribute__((ext_vector_type(8))) short bf16x8;
typedef __attribute__((ext_vector_type(4))) float f32x4;

constexpr int B_ = 4, S_ = 1024, D_ = 4096, H_ = 32, HKV_ = 8, HD_ = 128;
constexpr int BS_ = B_ * S_;                 // 4096 tokens
constexpr int NQKV_ = (H_ + 2 * HKV_) * HD_; // 6144
constexpr float ATT_SCALE = 0.08838834764831845f; // 1/sqrt(128)
constexpr float LOG2E = 1.4426950408889634f;

DEVI unsigned short f2b(float f) {
  union { float f; uint32_t u; } x; x.f = f;
  uint32_t r = x.u + 0x7fffu + ((x.u >> 16) & 1u);
  return (unsigned short)(r >> 16);
}
DEVI float b2f(unsigned short b) {
  union { uint32_t u; float f; } x; x.u = ((uint32_t)b) << 16;
  return x.f;
}

#define GLOBAL_AS(p) ((__attribute__((address_space(1))) void*)(p))
#define LDS_AS(p)    ((__attribute__((address_space(3))) void*)(p))

// ---------------- fp32 -> bf16 elementwise convert (vectorized) ----------------
__global__ void cvt_bf16_kernel(const float* __restrict__ src,
                                unsigned short* __restrict__ dst, int n4) {
  int i = blockIdx.x * blockDim.x + threadIdx.x;
  int stride = gridDim.x * blockDim.x;
  for (; i < n4; i += stride) {
    float4 v = ((const float4*)src)[i];
    ushort4 o;
    o.x = f2b(v.x); o.y = f2b(v.y); o.z = f2b(v.z); o.w = f2b(v.w);
    ((ushort4*)dst)[i] = o;
  }
}

// ---------------- fp32 (R x C) -> bf16 (C x R) tiled transpose-convert ----------------
__global__ void transpose_cvt_kernel(const float* __restrict__ src,
                                     unsigned short* __restrict__ dst,
                                     int R, int C) {
  __shared__ unsigned short tile[32][33];
  int tx = threadIdx.x & 31, ty = threadIdx.x >> 5; // 32 x 8
  int r0 = blockIdx.y * 32, c0 = blockIdx.x * 32;
  #pragma unroll
  for (int j = 0; j < 4; ++j) {
    int r = ty * 4 + j;
    tile[r][tx] = f2b(src[(size_t)(r0 + r) * C + (c0 + tx)]);
  }
  __syncthreads();
  #pragma unroll
  for (int j = 0; j < 4; ++j) {
    int c = ty * 4 + j;
    dst[(size_t)(c0 + c) * R + (r0 + tx)] = tile[tx][c];
  }
}

// ---------------- GEMM: C(MxN) = A(MxK) * Bt(NxK)^T, bf16 in, OutT out ----------------
// m97 structure: 128x128 tile, BK=32, 4 waves each 64x64, global_load_lds width 16.
template <typename OutT>
__global__ __launch_bounds__(256) void gemm_bt_kernel(
    const unsigned short* __restrict__ A,
    const unsigned short* __restrict__ Bt,
    OutT* __restrict__ C, int M, int N, int K) {
  constexpr int BK = 32;
  __shared__ unsigned short As[128 * BK];
  __shared__ unsigned short Bs[128 * BK];
  const int m0 = blockIdx.y * 128, n0 = blockIdx.x * 128;
  const int tid = threadIdx.x, lane = tid & 63, w = tid >> 6;
  const int wr = w >> 1, wc = w & 1;
  const int lrow = lane & 15, lk8 = (lane >> 4) * 8;

  f32x4 acc[4][4];
  #pragma unroll
  for (int i = 0; i < 4; ++i)
    #pragma unroll
    for (int j = 0; j < 4; ++j) acc[i][j] = (f32x4)0.0f;

  for (int kt = 0; kt < K; kt += BK) {
    #pragma unroll
    for (int i = 0; i < 2; ++i) {
      int e = (w * 2 + i) * 512 + lane * 8;  // element index in 128x32 tile
      int r = e >> 5, c = e & 31;
      __builtin_amdgcn_global_load_lds(GLOBAL_AS(A + (size_t)(m0 + r) * K + kt + c),
                                       LDS_AS(As + (w * 2 + i) * 512), 16, 0, 0);
      __builtin_amdgcn_global_load_lds(GLOBAL_AS(Bt + (size_t)(n0 + r) * K + kt + c),
                                       LDS_AS(Bs + (w * 2 + i) * 512), 16, 0, 0);
    }
    __syncthreads();
    bf16x8 af[4], bfr[4];
    #pragma unroll
    for (int i = 0; i < 4; ++i) {
      af[i]  = *(const bf16x8*)(As + (wr * 64 + i * 16 + lrow) * BK + lk8);
      bfr[i] = *(const bf16x8*)(Bs + (wc * 64 + i * 16 + lrow) * BK + lk8);
    }
    #pragma unroll
    for (int i = 0; i < 4; ++i)
      #pragma unroll
      for (int j = 0; j < 4; ++j)
        acc[i][j] = __builtin_amdgcn_mfma_f32_16x16x32_bf16(af[i], bfr[j], acc[i][j], 0, 0, 0);
    __syncthreads();
  }
  // C/D layout: col = lane&15, row = (lane>>4)*4 + reg  [m89-verified]
  const int rbase = m0 + wr * 64 + (lane >> 4) * 4;
  const int cbase = n0 + wc * 64 + lrow;
  #pragma unroll
  for (int i = 0; i < 4; ++i)
    #pragma unroll
    for (int j = 0; j < 4; ++j)
      #pragma unroll
      for (int r = 0; r < 4; ++r) {
        size_t idx = (size_t)(rbase + i * 16 + r) * N + (cbase + j * 16);
        if constexpr (sizeof(OutT) == 2) C[idx] = (OutT)f2b(acc[i][j][r]);
        else                              C[idx] = acc[i][j][r];
      }
}

// ---------------- RoPE + layout: qkv (BS,6144) -> Qr(B,H,S,HD), Kr(B,HKV,S,HD) ----------------
__global__ void rope_kernel(const unsigned short* __restrict__ qkv,
                            const float* __restrict__ rope_cos,
                            const float* __restrict__ rope_sin,
                            unsigned short* __restrict__ Qr,
                            unsigned short* __restrict__ Kr) {
  int bs = blockIdx.x;
  int b = bs >> 10, s = bs & 1023;
  int tid = threadIdx.x;
  __shared__ float cs[64], sn[64];
  if (tid < 64) cs[tid] = rope_cos[s * 64 + tid];
  else if (tid < 128) sn[tid - 64] = rope_sin[s * 64 + (tid - 64)];
  __syncthreads();
  const unsigned short* row = qkv + (size_t)bs * NQKV_;
  // Q: H*HD/2 = 2048 pairs
  for (int p = tid; p < 2048; p += 256) {
    int h = p >> 6, i = p & 63;
    uint32_t xx = *(const uint32_t*)(row + h * 128 + 2 * i);
    float x0 = b2f((unsigned short)(xx & 0xffffu));
    float x1 = b2f((unsigned short)(xx >> 16));
    float c = cs[i], d = sn[i];
    uint32_t oo = (uint32_t)f2b(x0 * c - x1 * d) | ((uint32_t)f2b(x0 * d + x1 * c) << 16);
    size_t o = ((size_t)(b * H_ + h) * S_ + s) * HD_ + 2 * i;
    *(uint32_t*)(Qr + o) = oo;
  }
  // K: 512 pairs
  for (int p = tid; p < 512; p += 256) {
    int hk = p >> 6, i = p & 63;
    uint32_t xx = *(const uint32_t*)(row + H_ * HD_ + hk * 128 + 2 * i);
    float x0 = b2f((unsigned short)(xx & 0xffffu));
    float x1 = b2f((unsigned short)(xx >> 16));
    float c = cs[i], d = sn[i];
    uint32_t oo = (uint32_t)f2b(x0 * c - x1 * d) | ((uint32_t)f2b(x0 * d + x1 * c) << 16);
    size_t o = ((size_t)(b * HKV_ + hk) * S_ + s) * HD_ + 2 * i;
    *(uint32_t*)(Kr + o) = oo;
  }
}

// ---------------- V transpose: qkv V-part (s,d) -> Vt (B,HKV,HD,S) ----------------
__global__ void vtrans_kernel(const unsigned short* __restrict__ qkv,
                              unsigned short* __restrict__ Vt) {
  __shared__ unsigned short tile[32][33];
  int bh = blockIdx.z;               // b*HKV + hkv
  int b = bh >> 3, hk = bh & 7;
  int s0 = blockIdx.x * 32, d0 = blockIdx.y * 32;
  int tx = threadIdx.x & 31, ty = threadIdx.x >> 5;
  #pragma unroll
  for (int j = 0; j < 4; ++j) {
    int r = ty * 4 + j;
    tile[r][tx] = qkv[(size_t)(b * S_ + s0 + r) * NQKV_ + (H_ + HKV_) * HD_ + hk * 128 + d0 + tx];
  }
  __syncthreads();
  #pragma unroll
  for (int j = 0; j < 4; ++j) {
    int d = ty * 4 + j;
    Vt[((size_t)bh * HD_ + d0 + d) * S_ + s0 + tx] = tile[tx][d];
  }
}

// ---------------- Flash attention: causal GQA ----------------
// grid (S/128, B*H), 256 threads = 4 waves x 32 q-rows; KV tiles of 64.
__global__ __launch_bounds__(256) void attn_kernel(
    const unsigned short* __restrict__ Qr,   // (B,H,S,HD)
    const unsigned short* __restrict__ Kr,   // (B,HKV,S,HD)
    const unsigned short* __restrict__ Vt,   // (B,HKV,HD,S)
    unsigned short* __restrict__ Oo) {       // (B,S,H*HD)
  __shared__ unsigned short Ks[64 * 128];    // [kv][hd]
  __shared__ unsigned short Vs[128 * 64];    // [hd][kv]
  __shared__ unsigned short Ps[4][32 * 64];  // per-wave P
  const int qt = blockIdx.x;
  const int bh = blockIdx.y;
  const int b = bh >> 5, h = bh & 31;
  const int hk = h >> 2;                     // REPEATS = 4
  const int tid = threadIdx.x, lane = tid & 63, w = tid >> 6;
  const int lrow = lane & 15, lg = lane >> 4, lk8 = lg * 8;
  const int q0 = qt * 128 + w * 32;

  const unsigned short* Qb = Qr + (size_t)(b * H_ + h) * S_ * HD_;
  bf16x8 qf[2][4];
  #pragma unroll
  for (int mf = 0; mf < 2; ++mf)
    #pragma unroll
    for (int kf = 0; kf < 4; ++kf)
      qf[mf][kf] = *(const bf16x8*)(Qb + (size_t)(q0 + mf * 16 + lrow) * HD_ + kf * 32 + lk8);

  f32x4 oacc[2][8];
  #pragma unroll
  for (int mf = 0; mf < 2; ++mf)
    #pragma unroll
    for (int nf = 0; nf < 8; ++nf) oacc[mf][nf] = (f32x4)0.0f;
  float m2[2][4], lsum[2][4];
  #pragma unroll
  for (int mf = 0; mf < 2; ++mf)
    #pragma unroll
    for (int r = 0; r < 4; ++r) { m2[mf][r] = -1.0e30f; lsum[mf][r] = 0.0f; }

  const int ntiles = (qt + 1) * 2;
  const unsigned short* Kb0 = Kr + (size_t)(b * HKV_ + hk) * S_ * HD_;
  const unsigned short* Vb0 = Vt + (size_t)(b * HKV_ + hk) * HD_ * S_;

  for (int kt = 0; kt < ntiles; ++kt) {
    const int k0 = kt * 64;
    const unsigned short* Kb = Kb0 + (size_t)k0 * HD_;
    #pragma unroll
    for (int i = 0; i < 4; ++i) {
      int e = (w * 4 + i) * 512 + lane * 8;
      __builtin_amdgcn_global_load_lds(GLOBAL_AS(Kb + e),
                                       LDS_AS(Ks + (w * 4 + i) * 512), 16, 0, 0);
      int dd = e >> 6, cc = e & 63;
      __builtin_amdgcn_global_load_lds(GLOBAL_AS(Vb0 + (size_t)dd * S_ + k0 + cc),
                                       LDS_AS(Vs + (w * 4 + i) * 512), 16, 0, 0);
    }
    __syncthreads();
    if (k0 <= q0 + 31) {  // wave-uniform causal skip
      f32x4 sacc[2][4];
      #pragma unroll
      for (int mf = 0; mf < 2; ++mf)
        #pragma unroll
        for (int nf = 0; nf < 4; ++nf) sacc[mf][nf] = (f32x4)0.0f;
      #pragma unroll
      for (int kf = 0; kf < 4; ++kf) {
        bf16x8 kfr[4];
        #pragma unroll
        for (int nf = 0; nf < 4; ++nf)
          kfr[nf] = *(const bf16x8*)(Ks + (nf * 16 + lrow) * 128 + kf * 32 + lk8);
        #pragma unroll
        for (int mf = 0; mf < 2; ++mf)
          #pragma unroll
          for (int nf = 0; nf < 4; ++nf)
            sacc[mf][nf] = __builtin_amdgcn_mfma_f32_16x16x32_bf16(qf[mf][kf], kfr[nf], sacc[mf][nf], 0, 0, 0);
      }
      const bool diag = (k0 + 63 > q0);
      #pragma unroll
      for (int mf = 0; mf < 2; ++mf)
        #pragma unroll
        for (int nf = 0; nf < 4; ++nf)
          #pragma unroll
          for (int r = 0; r < 4; ++r) {
            float v = sacc[mf][nf][r] * (ATT_SCALE * LOG2E);
            if (diag) {
              int qrow = q0 + mf * 16 + lg * 4 + r;
              int kcol = k0 + nf * 16 + lrow;
              v = (kcol > qrow) ? -3.0e38f : v;
            }
            sacc[mf][nf][r] = v;
          }
      // online softmax (exp2 domain); row owned by a 16-lane group
      #pragma unroll
      for (int mf = 0; mf < 2; ++mf)
        #pragma unroll
        for (int r = 0; r < 4; ++r) {
          float tm = fmaxf(fmaxf(sacc[mf][0][r], sacc[mf][1][r]),
                           fmaxf(sacc[mf][2][r], sacc[mf][3][r]));
          #pragma unroll
          for (int d = 1; d < 16; d <<= 1) tm = fmaxf(tm, __shfl_xor(tm, d, 64));
          float mo = m2[mf][r];
          float nm = fmaxf(mo, tm);
          float alpha = exp2f(mo - nm);
          m2[mf][r] = nm;
          float rs = 0.0f;
          #pragma unroll
          for (int nf = 0; nf < 4; ++nf) {
            float p = exp2f(sacc[mf][nf][r] - nm);
            sacc[mf][nf][r] = p;
            rs += p;
          }
          #pragma unroll
          for (int d = 1; d < 16; d <<= 1) rs += __shfl_xor(rs, d, 64);
          lsum[mf][r] = lsum[mf][r] * alpha + rs;
          #pragma unroll
          for (int nf = 0; nf < 8; ++nf) oacc[mf][nf][r] *= alpha;
        }
      // P -> per-wave LDS (bf16)
      unsigned short* Pw = &Ps[w][0];
      #pragma unroll
      for (int mf = 0; mf < 2; ++mf)
        #pragma unroll
        for (int nf = 0; nf < 4; ++nf)
          #pragma unroll
          for (int r = 0; r < 4; ++r)
            Pw[(mf * 16 + lg * 4 + r) * 64 + nf * 16 + lrow] = f2b(sacc[mf][nf][r]);
      // PV
      #pragma unroll
      for (int k2 = 0; k2 < 2; ++k2) {
        bf16x8 pa[2];
        #pragma unroll
        for (int mf = 0; mf < 2; ++mf)
          pa[mf] = *(const bf16x8*)(Pw + (mf * 16 + lrow) * 64 + k2 * 32 + lk8);
        #pragma unroll
        for (int nf = 0; nf < 8; ++nf) {
          bf16x8 vf = *(const bf16x8*)(Vs + (nf * 16 + lrow) * 64 + k2 * 32 + lk8);
          #pragma unroll
          for (int mf = 0; mf < 2; ++mf)
            oacc[mf][nf] = __builtin_amdgcn_mfma_f32_16x16x32_bf16(pa[mf], vf, oacc[mf][nf], 0, 0, 0);
        }
      }
    }
    __syncthreads();
  }
  // epilogue: O / lsum -> bf16 (B,S,H*HD)
  #pragma unroll
  for (int mf = 0; mf < 2; ++mf)
    #pragma unroll
    for (int r = 0; r < 4; ++r) {
      const int q = q0 + mf * 16 + lg * 4 + r;
      const float inv = 1.0f / lsum[mf][r];
      #pragma unroll
      for (int nf = 0; nf < 8; ++nf)
        Oo[(size_t)(b * S_ + q) * (H_ * HD_) + h * HD_ + nf * 16 + lrow] =
            f2b(oacc[mf][nf][r] * inv);
    }
}

// ---------------- launcher ----------------
// Workspace layout (128 MB total, regions reused across pipeline stages):
//   [0,32MB)   seq_bf16            -> later Qr
//   [32,80MB)  WqkvT (6144x4096)   -> later Kr(32..40), Vt(40..48), attn_out(48..80)
//   [80,128MB) qkv (4096x6144)     -> later WoT(80..112)
extern "C" void kernel_launch(void* const* d_in, const int* in_sizes, int n_in,
                              void* d_out, int out_size, void* d_ws, size_t ws_size,
                              hipStream_t stream) {
  const float* seq = (const float*)d_in[0];
  const float* Wq  = (const float*)d_in[1];
  const float* Wk  = (const float*)d_in[2];
  const float* Wv  = (const float*)d_in[3];
  const float* Wo  = (const float*)d_in[4];
  const float* rc  = (const float*)d_in[5];
  const float* rsn = (const float*)d_in[6];
  // d_in[7] = mask (tril, implemented analytically), d_in[8] = start_position (0)
  float* out = (float*)d_out;
  char* ws = (char*)d_ws;

  unsigned short* seqb  = (unsigned short*)(ws);
  unsigned short* WqkvT = (unsigned short*)(ws + (32ull << 20));
  unsigned short* qkv   = (unsigned short*)(ws + (80ull << 20));
  unsigned short* Qr    = (unsigned short*)(ws);
  unsigned short* Kr    = (unsigned short*)(ws + (32ull << 20));
  unsigned short* Vt    = (unsigned short*)(ws + (40ull << 20));
  unsigned short* attn  = (unsigned short*)(ws + (48ull << 20));
  unsigned short* WoT   = (unsigned short*)(ws + (80ull << 20));

  // 1) convert sequence to bf16
  cvt_bf16_kernel<<<2048, 256, 0, stream>>>(seq, seqb, BS_ * D_ / 4);
  // 2) transpose-convert weights into concatenated (N,K) bf16
  transpose_cvt_kernel<<<dim3(128, 128), 256, 0, stream>>>(Wq, WqkvT, D_, H_ * HD_);
  transpose_cvt_kernel<<<dim3(32, 128), 256, 0, stream>>>(
      Wk, WqkvT + (size_t)H_ * HD_ * D_, D_, HKV_ * HD_);
  transpose_cvt_kernel<<<dim3(32, 128), 256, 0, stream>>>(
      Wv, WqkvT + (size_t)(H_ + HKV_) * HD_ * D_, D_, HKV_ * HD_);
  // 3) QKV projection: (4096 x 6144) = seqb @ WqkvT^T
  gemm_bt_kernel<unsigned short><<<dim3(NQKV_ / 128, BS_ / 128), 256, 0, stream>>>(
      seqb, WqkvT, qkv, BS_, NQKV_, D_);
  // 4) RoPE -> Qr, Kr ; V transpose -> Vt
  rope_kernel<<<BS_, 256, 0, stream>>>(qkv, rc, rsn, Qr, Kr);
  vtrans_kernel<<<dim3(32, 4, 32), 256, 0, stream>>>(qkv, Vt);
  // 5) Wo transpose (into dead qkv region)
  transpose_cvt_kernel<<<dim3(128, 128), 256, 0, stream>>>(Wo, WoT, H_ * HD_, D_);
  // 6) causal GQA flash attention
  attn_kernel<<<dim3(S_ / 128, B_ * H_), 256, 0, stream>>>(Qr, Kr, Vt, attn);
  // 7) output projection -> fp32 out
  gemm_bt_kernel<float><<<dim3(D_ / 128, BS_ / 128), 256, 0, stream>>>(
      attn, WoT, out, BS_, D_, D_);
}

// Round 2
// 862.240 us; speedup vs baseline: 1.1732x; 1.1732x over previous
//
#include <hip/hip_runtime.h>
#include <hip/hip_bf16.h>
#include <stdint.h>

#define DEVI __device__ __forceinline__

typedef __attribute__((ext_vector_type(8))) short bf16x8;
typedef __attribute__((ext_vector_type(4))) float f32x4;

constexpr int B_ = 4, S_ = 1024, D_ = 4096, H_ = 32, HKV_ = 8, HD_ = 128;
constexpr int BS_ = B_ * S_;                 // 4096 tokens
constexpr int NQKV_ = (H_ + 2 * HKV_) * HD_; // 6144
constexpr float ATT_SCALE = 0.08838834764831845f; // 1/sqrt(128)
constexpr float LOG2E = 1.4426950408889634f;

DEVI unsigned short f2b(float f) {
  union { float f; uint32_t u; } x; x.f = f;
  uint32_t r = x.u + 0x7fffu + ((x.u >> 16) & 1u);
  return (unsigned short)(r >> 16);
}
DEVI float b2f(unsigned short b) {
  union { uint32_t u; float f; } x; x.u = ((uint32_t)b) << 16;
  return x.f;
}

#define GAS(p) ((__attribute__((address_space(1))) void*)(p))
#define LAS(p) ((__attribute__((address_space(3))) void*)(p))
#define BAR() __builtin_amdgcn_s_barrier()
#define SETPRIO(x) __builtin_amdgcn_s_setprio(x)
#define VMCNT4() do { asm volatile("s_waitcnt vmcnt(4)" ::: "memory"); __builtin_amdgcn_sched_barrier(0); } while (0)
#define VMCNT0() do { asm volatile("s_waitcnt vmcnt(0)" ::: "memory"); __builtin_amdgcn_sched_barrier(0); } while (0)

// ---------------- fp32 -> bf16 elementwise convert (vectorized) ----------------
__global__ void cvt_bf16_kernel(const float* __restrict__ src,
                                unsigned short* __restrict__ dst, int n4) {
  int i = blockIdx.x * blockDim.x + threadIdx.x;
  int stride = gridDim.x * blockDim.x;
  for (; i < n4; i += stride) {
    float4 v = ((const float4*)src)[i];
    ushort4 o;
    o.x = f2b(v.x); o.y = f2b(v.y); o.z = f2b(v.z); o.w = f2b(v.w);
    ((ushort4*)dst)[i] = o;
  }
}

// ---------------- fp32 (R x C) -> bf16 (C x R) tiled transpose-convert ----------------
__global__ void transpose_cvt_kernel(const float* __restrict__ src,
                                     unsigned short* __restrict__ dst,
                                     int R, int C) {
  __shared__ unsigned short tile[32][33];
  int tx = threadIdx.x & 31, ty = threadIdx.x >> 5; // 32 x 8
  int r0 = blockIdx.y * 32, c0 = blockIdx.x * 32;
  #pragma unroll
  for (int j = 0; j < 4; ++j) {
    int r = ty * 4 + j;
    tile[r][tx] = f2b(src[(size_t)(r0 + r) * C + (c0 + tx)]);
  }
  __syncthreads();
  #pragma unroll
  for (int j = 0; j < 4; ++j) {
    int c = ty * 4 + j;
    dst[(size_t)(c0 + c) * R + (r0 + tx)] = tile[tx][c];
  }
}

// ---------------- 256x256 8-phase GEMM: C(MxN)=A(MxK)*Bt(NxK)^T ----------------
// 512 thr = 8 waves (2M x 4N), BK=64, 128 KiB LDS dbuf, XOR-swizzled tiles,
// counted vmcnt(4) at phases p3/p7 only, XCD-swizzled block id.
// LDS map (ushort units): A-buf b @ b*16384, B-buf b @ 32768+b*16384,
// half h within a buf @ h*8192 (rows h*128..h*128+127, row stride 64).
template <typename OutT>
__global__ __launch_bounds__(512, 2) void gemm256_kernel(
    const unsigned short* __restrict__ A,
    const unsigned short* __restrict__ Bt,
    OutT* __restrict__ C, int M, int N, int K) {
  __shared__ unsigned short L[4 * 16384];  // 128 KiB
  const int tid = threadIdx.x, lane = tid & 63, w = tid >> 6;
  const int lrow = lane & 15, lg = lane >> 4;
  const int wm = w >> 2, wn = w & 3;

  const int nbx = N >> 8;
  const int nblk = gridDim.x;
  int id = blockIdx.x;
  int swz = ((nblk & 7) == 0) ? ((id & 7) * (nblk >> 3) + (id >> 3)) : id;
  const int m0 = (swz / nbx) << 8, n0 = (swz % nbx) << 8;

  const int NT = K >> 6, NI = NT >> 1;

  // staging per-lane constants: chunk (row sub sr, col chunk sc), source col
  // pre-swizzled so that linear LDS dest + XOR read = consistent involution.
  const int sr = lane >> 3, sc = lane & 7;
  const int scx = (sc ^ sr) * 8;  // swizzled source column (elements)

  // fragment read offsets (ushort units) per k-step
  int aoff[2], boff[2];
  #pragma unroll
  for (int ks = 0; ks < 2; ++ks) {
    int cp = ((ks * 4 + lg) ^ (lrow & 7)) * 8;
    aoff[ks] = wm * 8192 + lrow * 64 + cp;
    boff[ks] = wn * 4096 + lrow * 64 + cp;
  }

  f32x4 acc[8][4];
  #pragma unroll
  for (int m = 0; m < 8; ++m)
    #pragma unroll
    for (int n = 0; n < 4; ++n) acc[m][n] = (f32x4)0.0f;

  auto stageA = [&](int buf, int half, int t) {
    unsigned short* base = L + buf * 16384 + half * 8192;
    const unsigned short* src = A + (size_t)(m0 + half * 128) * K + (size_t)t * 64;
    #pragma unroll
    for (int j = 0; j < 2; ++j) {
      int rl = (w * 2 + j) * 8 + sr;
      __builtin_amdgcn_global_load_lds(GAS(src + (size_t)rl * K + scx),
                                       LAS(base + (w * 2 + j) * 512), 16, 0, 0);
    }
  };
  auto stageB = [&](int buf, int half, int t) {
    unsigned short* base = L + 32768 + buf * 16384 + half * 8192;
    const unsigned short* src = Bt + (size_t)(n0 + half * 128) * K + (size_t)t * 64;
    #pragma unroll
    for (int j = 0; j < 2; ++j) {
      int rl = (w * 2 + j) * 8 + sr;
      __builtin_amdgcn_global_load_lds(GAS(src + (size_t)rl * K + scx),
                                       LAS(base + (w * 2 + j) * 512), 16, 0, 0);
    }
  };

  bf16x8 a0[4][2], a1[4][2], b[4][2];
  auto ldA = [&](bf16x8 (&dst)[4][2], const unsigned short* Ab, int mbase) {
    #pragma unroll
    for (int m = 0; m < 4; ++m)
      #pragma unroll
      for (int ks = 0; ks < 2; ++ks)
        dst[m][ks] = *(const bf16x8*)(Ab + aoff[ks] + (mbase + m) * 1024);
  };
  auto ldB01 = [&](const unsigned short* Bb) {
    #pragma unroll
    for (int n = 0; n < 2; ++n)
      #pragma unroll
      for (int ks = 0; ks < 2; ++ks)
        b[n][ks] = *(const bf16x8*)(Bb + boff[ks] + n * 1024);
  };
  auto ldB23 = [&](const unsigned short* Bb) {
    #pragma unroll
    for (int n = 0; n < 2; ++n)
      #pragma unroll
      for (int ks = 0; ks < 2; ++ks)
        b[2 + n][ks] = *(const bf16x8*)(Bb + boff[ks] + (2 + n) * 1024);
  };

#define QUAD(am, MQ, NQ)                                                        \
  do {                                                                          \
    SETPRIO(1);                                                                 \
    _Pragma("unroll") for (int m = 0; m < 4; ++m) {                             \
      _Pragma("unroll") for (int n = 0; n < 2; ++n) {                           \
        _Pragma("unroll") for (int ks = 0; ks < 2; ++ks) {                      \
          acc[(MQ)*4 + m][(NQ)*2 + n] = __builtin_amdgcn_mfma_f32_16x16x32_bf16(\
              am[m][ks], b[(NQ)*2 + n][ks], acc[(MQ)*4 + m][(NQ)*2 + n], 0, 0, 0);\
        }                                                                       \
      }                                                                         \
    }                                                                           \
    SETPRIO(0);                                                                 \
  } while (0)

  // prologue: t0 fully (B0,B1,A0,A1), t1 B halves. vmcnt(4) leaves t1:B in flight.
  stageB(0, 0, 0); stageB(0, 1, 0); stageA(0, 0, 0); stageA(0, 1, 0);
  stageB(1, 0, 1); stageB(1, 1, 1);
  VMCNT4(); BAR();

  const unsigned short* Ab0 = L;
  const unsigned short* Bb0 = L + 32768;
  const unsigned short* Ab1 = L + 16384;
  const unsigned short* Bb1 = L + 49152;

  for (int it = 0; it < NI; ++it) {
    const int t_odd = 2 * it + 1, t_e2 = 2 * it + 2, t_o3 = 2 * it + 3;
    const bool s2 = t_e2 < NT, s3 = t_o3 < NT, lastit = (it == NI - 1);
    // ---- even tile (buf0) ----
    // p0
    ldA(a0, Ab0, 0); ldB01(Bb0);
    stageA(1, 0, t_odd);
    BAR(); QUAD(a0, 0, 0); BAR();
    // p1
    ldB23(Bb0);
    stageA(1, 1, t_odd);
    BAR(); QUAD(a0, 0, 1); BAR();
    // p2
    ldA(a1, Ab0, 4);
    if (s2) stageB(0, 0, t_e2);
    BAR(); QUAD(a1, 1, 0); BAR();
    // p3  (gate: tile t_odd fully staged before p4-p6 reads)
    if (s2) stageB(0, 1, t_e2);
    if (lastit) { VMCNT0(); } else { VMCNT4(); }
    BAR(); QUAD(a1, 1, 1); BAR();
    // ---- odd tile (buf1) ----
    // p4
    ldA(a0, Ab1, 0); ldB01(Bb1);
    if (s2) stageA(0, 0, t_e2);
    BAR(); QUAD(a0, 0, 0); BAR();
    // p5
    ldB23(Bb1);
    if (s2) stageA(0, 1, t_e2);
    BAR(); QUAD(a0, 0, 1); BAR();
    // p6
    ldA(a1, Ab1, 4);
    if (s3) stageB(1, 0, t_o3);
    BAR(); QUAD(a1, 1, 0); BAR();
    // p7  (gate: tile t_e2 fully staged before next p0-p2 reads)
    if (s3) stageB(1, 1, t_o3);
    if (!lastit) { VMCNT4(); }
    BAR(); QUAD(a1, 1, 1); BAR();
  }
#undef QUAD

  // epilogue: C/D layout col=lane&15, row=(lane>>4)*4+reg
  const int rb = m0 + wm * 128 + lg * 4;
  const int cb = n0 + wn * 64 + lrow;
  #pragma unroll
  for (int m = 0; m < 8; ++m)
    #pragma unroll
    for (int n = 0; n < 4; ++n)
      #pragma unroll
      for (int r = 0; r < 4; ++r) {
        size_t idx = (size_t)(rb + m * 16 + r) * N + (cb + n * 16);
        if constexpr (sizeof(OutT) == 2) C[idx] = (OutT)f2b(acc[m][n][r]);
        else                              C[idx] = acc[m][n][r];
      }
}

// ---------------- RoPE + layout: qkv (BS,6144) -> Qr(B,H,S,HD), Kr(B,HKV,S,HD) ----------------
__global__ void rope_kernel(const unsigned short* __restrict__ qkv,
                            const float* __restrict__ rope_cos,
                            const float* __restrict__ rope_sin,
                            unsigned short* __restrict__ Qr,
                            unsigned short* __restrict__ Kr) {
  int bs = blockIdx.x;
  int b = bs >> 10, s = bs & 1023;
  int tid = threadIdx.x;
  __shared__ float cs[64], sn[64];
  if (tid < 64) cs[tid] = rope_cos[s * 64 + tid];
  else if (tid < 128) sn[tid - 64] = rope_sin[s * 64 + (tid - 64)];
  __syncthreads();
  const unsigned short* row = qkv + (size_t)bs * NQKV_;
  for (int p = tid; p < 2048; p += 256) {
    int h = p >> 6, i = p & 63;
    uint32_t xx = *(const uint32_t*)(row + h * 128 + 2 * i);
    float x0 = b2f((unsigned short)(xx & 0xffffu));
    float x1 = b2f((unsigned short)(xx >> 16));
    float c = cs[i], d = sn[i];
    uint32_t oo = (uint32_t)f2b(x0 * c - x1 * d) | ((uint32_t)f2b(x0 * d + x1 * c) << 16);
    size_t o = ((size_t)(b * H_ + h) * S_ + s) * HD_ + 2 * i;
    *(uint32_t*)(Qr + o) = oo;
  }
  for (int p = tid; p < 512; p += 256) {
    int hk = p >> 6, i = p & 63;
    uint32_t xx = *(const uint32_t*)(row + H_ * HD_ + hk * 128 + 2 * i);
    float x0 = b2f((unsigned short)(xx & 0xffffu));
    float x1 = b2f((unsigned short)(xx >> 16));
    float c = cs[i], d = sn[i];
    uint32_t oo = (uint32_t)f2b(x0 * c - x1 * d) | ((uint32_t)f2b(x0 * d + x1 * c) << 16);
    size_t o = ((size_t)(b * HKV_ + hk) * S_ + s) * HD_ + 2 * i;
    *(uint32_t*)(Kr + o) = oo;
  }
}

// ---------------- V transpose: qkv V-part (s,d) -> Vt (B,HKV,HD,S) ----------------
__global__ void vtrans_kernel(const unsigned short* __restrict__ qkv,
                              unsigned short* __restrict__ Vt) {
  __shared__ unsigned short tile[32][33];
  int bh = blockIdx.z;
  int b = bh >> 3, hk = bh & 7;
  int s0 = blockIdx.x * 32, d0 = blockIdx.y * 32;
  int tx = threadIdx.x & 31, ty = threadIdx.x >> 5;
  #pragma unroll
  for (int j = 0; j < 4; ++j) {
    int r = ty * 4 + j;
    tile[r][tx] = qkv[(size_t)(b * S_ + s0 + r) * NQKV_ + (H_ + HKV_) * HD_ + hk * 128 + d0 + tx];
  }
  __syncthreads();
  #pragma unroll
  for (int j = 0; j < 4; ++j) {
    int d = ty * 4 + j;
    Vt[((size_t)bh * HD_ + d0 + d) * S_ + s0 + tx] = tile[tx][d];
  }
}

// ---------------- Flash attention: causal GQA, swizzled LDS + K/V dbuf ----------------
// grid (S/128, B*H), 256 threads = 4 waves x 32 q-rows; KV tiles of 64.
__global__ __launch_bounds__(256) void attn_kernel(
    const unsigned short* __restrict__ Qr,   // (B,H,S,HD)
    const unsigned short* __restrict__ Kr,   // (B,HKV,S,HD)
    const unsigned short* __restrict__ Vt,   // (B,HKV,HD,S)
    unsigned short* __restrict__ Oo) {       // (B,S,H*HD)
  __shared__ unsigned short Ks[2][64 * 128];
  __shared__ unsigned short Vs[2][128 * 64];
  __shared__ unsigned short Ps[4][32 * 64];
  const int qt = blockIdx.x;
  const int bh = blockIdx.y;
  const int b = bh >> 5, h = bh & 31;
  const int hk = h >> 2;
  const int tid = threadIdx.x, lane = tid & 63, w = tid >> 6;
  const int lrow = lane & 15, lg = lane >> 4, lk8 = lg * 8;
  const int cxor = lrow & 7;   // read-side swizzle key
  const int q0 = qt * 128 + w * 32;

  const unsigned short* Qb = Qr + (size_t)(b * H_ + h) * S_ * HD_;
  bf16x8 qf[2][4];
  #pragma unroll
  for (int mf = 0; mf < 2; ++mf)
    #pragma unroll
    for (int kf = 0; kf < 4; ++kf)
      qf[mf][kf] = *(const bf16x8*)(Qb + (size_t)(q0 + mf * 16 + lrow) * HD_ + kf * 32 + lk8);

  f32x4 oacc[2][8];
  #pragma unroll
  for (int mf = 0; mf < 2; ++mf)
    #pragma unroll
    for (int nf = 0; nf < 8; ++nf) oacc[mf][nf] = (f32x4)0.0f;
  float m2[2][4], lsum[2][4];
  #pragma unroll
  for (int mf = 0; mf < 2; ++mf)
    #pragma unroll
    for (int r = 0; r < 4; ++r) { m2[mf][r] = -1.0e30f; lsum[mf][r] = 0.0f; }

  const int ntiles = (qt + 1) * 2;
  const unsigned short* Kb0 = Kr + (size_t)(b * HKV_ + hk) * S_ * HD_;
  const unsigned short* Vb0 = Vt + (size_t)(b * HKV_ + hk) * HD_ * S_;

  // staging: LDS linear dest, source pre-swizzled (chunk c -> c ^ (row&7))
  auto stage = [&](int bb, int kt) {
    const int k0s = kt * 64;
    #pragma unroll
    for (int i = 0; i < 4; ++i) {
      int kr = (w * 4 + i) * 4 + lg;          // K tile row (0..63)
      int kcs = ((lane & 15) ^ (kr & 7)) * 8; // swizzled col (elements)
      __builtin_amdgcn_global_load_lds(GAS(Kb0 + (size_t)(k0s + kr) * HD_ + kcs),
                                       LAS(Ks[bb] + (w * 4 + i) * 512), 16, 0, 0);
      int vr = (w * 4 + i) * 8 + (lane >> 3); // V tile row = hd (0..127)
      int vcs = ((lane & 7) ^ (lane >> 3)) * 8;
      __builtin_amdgcn_global_load_lds(GAS(Vb0 + (size_t)vr * S_ + k0s + vcs),
                                       LAS(Vs[bb] + (w * 4 + i) * 512), 16, 0, 0);
    }
  };

  stage(0, 0);
  __syncthreads();

  for (int kt = 0; kt < ntiles; ++kt) {
    if (kt + 1 < ntiles) stage((kt + 1) & 1, kt + 1);
    const unsigned short* Ksb = Ks[kt & 1];
    const unsigned short* Vsb = Vs[kt & 1];
    const int k0 = kt * 64;
    if (k0 <= q0 + 31) {  // wave-uniform causal skip
      f32x4 sacc[2][4];
      #pragma unroll
      for (int mf = 0; mf < 2; ++mf)
        #pragma unroll
        for (int nf = 0; nf < 4; ++nf) sacc[mf][nf] = (f32x4)0.0f;
      #pragma unroll
      for (int kf = 0; kf < 4; ++kf) {
        bf16x8 kfr[4];
        #pragma unroll
        for (int nf = 0; nf < 4; ++nf)
          kfr[nf] = *(const bf16x8*)(Ksb + (nf * 16 + lrow) * 128 + ((kf * 4 + lg) ^ cxor) * 8);
        SETPRIO(1);
        #pragma unroll
        for (int mf = 0; mf < 2; ++mf)
          #pragma unroll
          for (int nf = 0; nf < 4; ++nf)
            sacc[mf][nf] = __builtin_amdgcn_mfma_f32_16x16x32_bf16(qf[mf][kf], kfr[nf], sacc[mf][nf], 0, 0, 0);
        SETPRIO(0);
      }
      const bool diag = (k0 + 63 > q0);
      #pragma unroll
      for (int mf = 0; mf < 2; ++mf)
        #pragma unroll
        for (int nf = 0; nf < 4; ++nf)
          #pragma unroll
          for (int r = 0; r < 4; ++r) {
            float v = sacc[mf][nf][r] * (ATT_SCALE * LOG2E);
            if (diag) {
              int qrow = q0 + mf * 16 + lg * 4 + r;
              int kcol = k0 + nf * 16 + lrow;
              v = (kcol > qrow) ? -3.0e38f : v;
            }
            sacc[mf][nf][r] = v;
          }
      // online softmax (exp2 domain)
      #pragma unroll
      for (int mf = 0; mf < 2; ++mf)
        #pragma unroll
        for (int r = 0; r < 4; ++r) {
          float tm = fmaxf(fmaxf(sacc[mf][0][r], sacc[mf][1][r]),
                           fmaxf(sacc[mf][2][r], sacc[mf][3][r]));
          #pragma unroll
          for (int d = 1; d < 16; d <<= 1) tm = fmaxf(tm, __shfl_xor(tm, d, 64));
          float mo = m2[mf][r];
          float nm = fmaxf(mo, tm);
          float alpha = exp2f(mo - nm);
          m2[mf][r] = nm;
          float rs = 0.0f;
          #pragma unroll
          for (int nf = 0; nf < 4; ++nf) {
            float p = exp2f(sacc[mf][nf][r] - nm);
            sacc[mf][nf][r] = p;
            rs += p;
          }
          #pragma unroll
          for (int d = 1; d < 16; d <<= 1) rs += __shfl_xor(rs, d, 64);
          lsum[mf][r] = lsum[mf][r] * alpha + rs;
          #pragma unroll
          for (int nf = 0; nf < 8; ++nf) oacc[mf][nf][r] *= alpha;
        }
      // P -> per-wave LDS (swizzled write)
      unsigned short* Pw = &Ps[w][0];
      #pragma unroll
      for (int mf = 0; mf < 2; ++mf)
        #pragma unroll
        for (int nf = 0; nf < 4; ++nf)
          #pragma unroll
          for (int r = 0; r < 4; ++r) {
            int prow = mf * 16 + lg * 4 + r;
            int pcol = nf * 16 + lrow;
            Pw[prow * 64 + (pcol ^ ((prow & 7) << 3))] = f2b(sacc[mf][nf][r]);
          }
      // PV (swizzled reads)
      #pragma unroll
      for (int k2 = 0; k2 < 2; ++k2) {
        bf16x8 pa[2];
        #pragma unroll
        for (int mf = 0; mf < 2; ++mf)
          pa[mf] = *(const bf16x8*)(Pw + (mf * 16 + lrow) * 64 + ((k2 * 4 + lg) ^ cxor) * 8);
        SETPRIO(1);
        #pragma unroll
        for (int nf = 0; nf < 8; ++nf) {
          bf16x8 vf = *(const bf16x8*)(Vsb + (nf * 16 + lrow) * 64 + ((k2 * 4 + lg) ^ cxor) * 8);
          #pragma unroll
          for (int mf = 0; mf < 2; ++mf)
            oacc[mf][nf] = __builtin_amdgcn_mfma_f32_16x16x32_bf16(pa[mf], vf, oacc[mf][nf], 0, 0, 0);
        }
        SETPRIO(0);
      }
    }
    __syncthreads();
  }
  #pragma unroll
  for (int mf = 0; mf < 2; ++mf)
    #pragma unroll
    for (int r = 0; r < 4; ++r) {
      const int q = q0 + mf * 16 + lg * 4 + r;
      const float inv = 1.0f / lsum[mf][r];
      #pragma unroll
      for (int nf = 0; nf < 8; ++nf)
        Oo[(size_t)(b * S_ + q) * (H_ * HD_) + h * HD_ + nf * 16 + lrow] =
            f2b(oacc[mf][nf][r] * inv);
    }
}

// ---------------- launcher ----------------
// Workspace layout (128 MB, regions reused):
//   [0,32MB)   seq_bf16            -> later Qr
//   [32,80MB)  WqkvT (6144x4096)   -> later Kr(32..40), Vt(40..48), attn_out(48..80)
//   [80,128MB) qkv (4096x6144)     -> later WoT(80..112)
extern "C" void kernel_launch(void* const* d_in, const int* in_sizes, int n_in,
                              void* d_out, int out_size, void* d_ws, size_t ws_size,
                              hipStream_t stream) {
  const float* seq = (const float*)d_in[0];
  const float* Wq  = (const float*)d_in[1];
  const float* Wk  = (const float*)d_in[2];
  const float* Wv  = (const float*)d_in[3];
  const float* Wo  = (const float*)d_in[4];
  const float* rc  = (const float*)d_in[5];
  const float* rsn = (const float*)d_in[6];
  float* out = (float*)d_out;
  char* ws = (char*)d_ws;

  unsigned short* seqb  = (unsigned short*)(ws);
  unsigned short* WqkvT = (unsigned short*)(ws + (32ull << 20));
  unsigned short* qkv   = (unsigned short*)(ws + (80ull << 20));
  unsigned short* Qr    = (unsigned short*)(ws);
  unsigned short* Kr    = (unsigned short*)(ws + (32ull << 20));
  unsigned short* Vt    = (unsigned short*)(ws + (40ull << 20));
  unsigned short* attn  = (unsigned short*)(ws + (48ull << 20));
  unsigned short* WoT   = (unsigned short*)(ws + (80ull << 20));

  cvt_bf16_kernel<<<2048, 256, 0, stream>>>(seq, seqb, BS_ * D_ / 4);
  transpose_cvt_kernel<<<dim3(128, 128), 256, 0, stream>>>(Wq, WqkvT, D_, H_ * HD_);
  transpose_cvt_kernel<<<dim3(32, 128), 256, 0, stream>>>(
      Wk, WqkvT + (size_t)H_ * HD_ * D_, D_, HKV_ * HD_);
  transpose_cvt_kernel<<<dim3(32, 128), 256, 0, stream>>>(
      Wv, WqkvT + (size_t)(H_ + HKV_) * HD_ * D_, D_, HKV_ * HD_);
  // QKV projection: (4096 x 6144)
  gemm256_kernel<unsigned short><<<dim3((BS_ / 256) * (NQKV_ / 256)), 512, 0, stream>>>(
      seqb, WqkvT, qkv, BS_, NQKV_, D_);
  rope_kernel<<<BS_, 256, 0, stream>>>(qkv, rc, rsn, Qr, Kr);
  vtrans_kernel<<<dim3(32, 4, 32), 256, 0, stream>>>(qkv, Vt);
  transpose_cvt_kernel<<<dim3(128, 128), 256, 0, stream>>>(Wo, WoT, H_ * HD_, D_);
  attn_kernel<<<dim3(S_ / 128, B_ * H_), 256, 0, stream>>>(Qr, Kr, Vt, attn);
  // output projection -> fp32 out
  gemm256_kernel<float><<<dim3((BS_ / 256) * (D_ / 256)), 512, 0, stream>>>(
      attn, WoT, out, BS_, D_, D_);
}

// Round 4
// 699.048 us; speedup vs baseline: 1.4471x; 1.2334x over previous
//
#include <hip/hip_runtime.h>
#include <hip/hip_bf16.h>
#include <stdint.h>

#define DEVI __device__ __forceinline__

typedef __attribute__((ext_vector_type(8))) short bf16x8;
typedef __attribute__((ext_vector_type(4))) float f32x4;
typedef __attribute__((ext_vector_type(16))) float f32x16;

constexpr int B_ = 4, S_ = 1024, D_ = 4096, H_ = 32, HKV_ = 8, HD_ = 128;
constexpr int BS_ = B_ * S_;                 // 4096 tokens
constexpr int NQKV_ = (H_ + 2 * HKV_) * HD_; // 6144
constexpr float ATT_SCALE = 0.08838834764831845f; // 1/sqrt(128)
constexpr float LOG2E = 1.4426950408889634f;
constexpr float C1 = ATT_SCALE * LOG2E;

DEVI unsigned short f2b(float f) {
  union { float f; uint32_t u; } x; x.f = f;
  uint32_t r = x.u + 0x7fffu + ((x.u >> 16) & 1u);
  return (unsigned short)(r >> 16);
}
DEVI float b2f(unsigned short b) {
  union { uint32_t u; float f; } x; x.u = ((uint32_t)b) << 16;
  return x.f;
}
DEVI uint32_t cvt_pk_bf16(float lo, float hi_) {
  uint32_t r;
  asm("v_cvt_pk_bf16_f32 %0, %1, %2" : "=v"(r) : "v"(lo), "v"(hi_));
  return r;
}

#define GAS(p) ((__attribute__((address_space(1))) void*)(p))
#define LAS(p) ((__attribute__((address_space(3))) void*)(p))
#define BAR() __builtin_amdgcn_s_barrier()
#define SETPRIO(x) __builtin_amdgcn_s_setprio(x)
#define VMCNT4() do { asm volatile("s_waitcnt vmcnt(4)" ::: "memory"); __builtin_amdgcn_sched_barrier(0); } while (0)
#define VMCNT0() do { asm volatile("s_waitcnt vmcnt(0)" ::: "memory"); __builtin_amdgcn_sched_barrier(0); } while (0)

// ---------------- fp32 -> bf16 elementwise convert (vectorized) ----------------
__global__ void cvt_bf16_kernel(const float* __restrict__ src,
                                unsigned short* __restrict__ dst, int n4) {
  int i = blockIdx.x * blockDim.x + threadIdx.x;
  int stride = gridDim.x * blockDim.x;
  for (; i < n4; i += stride) {
    float4 v = ((const float4*)src)[i];
    ushort4 o;
    o.x = f2b(v.x); o.y = f2b(v.y); o.z = f2b(v.z); o.w = f2b(v.w);
    ((ushort4*)dst)[i] = o;
  }
}

// ---------------- fp32 (R x C) -> bf16 (C x R) tiled transpose-convert ----------------
__global__ void transpose_cvt_kernel(const float* __restrict__ src,
                                     unsigned short* __restrict__ dst,
                                     int R, int C) {
  __shared__ unsigned short tile[32][33];
  int tx = threadIdx.x & 31, ty = threadIdx.x >> 5; // 32 x 8
  int r0 = blockIdx.y * 32, c0 = blockIdx.x * 32;
  #pragma unroll
  for (int j = 0; j < 4; ++j) {
    int r = ty * 4 + j;
    tile[r][tx] = f2b(src[(size_t)(r0 + r) * C + (c0 + tx)]);
  }
  __syncthreads();
  #pragma unroll
  for (int j = 0; j < 4; ++j) {
    int c = ty * 4 + j;
    dst[(size_t)(c0 + c) * R + (r0 + tx)] = tile[tx][c];
  }
}

// ---------------- 256x256 8-phase GEMM: C(MxN)=A(MxK)*Bt(NxK)^T ----------------
template <typename OutT>
__global__ __launch_bounds__(512, 2) void gemm256_kernel(
    const unsigned short* __restrict__ A,
    const unsigned short* __restrict__ Bt,
    OutT* __restrict__ C, int M, int N, int K) {
  __shared__ unsigned short L[4 * 16384];  // 128 KiB
  const int tid = threadIdx.x, lane = tid & 63, w = tid >> 6;
  const int lrow = lane & 15, lg = lane >> 4;
  const int wm = w >> 2, wn = w & 3;

  const int nbx = N >> 8;
  const int nblk = gridDim.x;
  int id = blockIdx.x;
  int swz = ((nblk & 7) == 0) ? ((id & 7) * (nblk >> 3) + (id >> 3)) : id;
  const int m0 = (swz / nbx) << 8, n0 = (swz % nbx) << 8;

  const int NT = K >> 6, NI = NT >> 1;

  const int sr = lane >> 3, sc = lane & 7;
  const int scx = (sc ^ sr) * 8;  // swizzled source column (elements)

  int aoff[2], boff[2];
  #pragma unroll
  for (int ks = 0; ks < 2; ++ks) {
    int cp = ((ks * 4 + lg) ^ (lrow & 7)) * 8;
    aoff[ks] = wm * 8192 + lrow * 64 + cp;
    boff[ks] = wn * 4096 + lrow * 64 + cp;
  }

  f32x4 acc[8][4];
  #pragma unroll
  for (int m = 0; m < 8; ++m)
    #pragma unroll
    for (int n = 0; n < 4; ++n) acc[m][n] = (f32x4)0.0f;

  auto stageA = [&](int buf, int half, int t) {
    unsigned short* base = L + buf * 16384 + half * 8192;
    const unsigned short* src = A + (size_t)(m0 + half * 128) * K + (size_t)t * 64;
    #pragma unroll
    for (int j = 0; j < 2; ++j) {
      int rl = (w * 2 + j) * 8 + sr;
      __builtin_amdgcn_global_load_lds(GAS(src + (size_t)rl * K + scx),
                                       LAS(base + (w * 2 + j) * 512), 16, 0, 0);
    }
  };
  auto stageB = [&](int buf, int half, int t) {
    unsigned short* base = L + 32768 + buf * 16384 + half * 8192;
    const unsigned short* src = Bt + (size_t)(n0 + half * 128) * K + (size_t)t * 64;
    #pragma unroll
    for (int j = 0; j < 2; ++j) {
      int rl = (w * 2 + j) * 8 + sr;
      __builtin_amdgcn_global_load_lds(GAS(src + (size_t)rl * K + scx),
                                       LAS(base + (w * 2 + j) * 512), 16, 0, 0);
    }
  };

  bf16x8 a0[4][2], a1[4][2], b[4][2];
  auto ldA = [&](bf16x8 (&dst)[4][2], const unsigned short* Ab, int mbase) {
    #pragma unroll
    for (int m = 0; m < 4; ++m)
      #pragma unroll
      for (int ks = 0; ks < 2; ++ks)
        dst[m][ks] = *(const bf16x8*)(Ab + aoff[ks] + (mbase + m) * 1024);
  };
  auto ldB01 = [&](const unsigned short* Bb) {
    #pragma unroll
    for (int n = 0; n < 2; ++n)
      #pragma unroll
      for (int ks = 0; ks < 2; ++ks)
        b[n][ks] = *(const bf16x8*)(Bb + boff[ks] + n * 1024);
  };
  auto ldB23 = [&](const unsigned short* Bb) {
    #pragma unroll
    for (int n = 0; n < 2; ++n)
      #pragma unroll
      for (int ks = 0; ks < 2; ++ks)
        b[2 + n][ks] = *(const bf16x8*)(Bb + boff[ks] + (2 + n) * 1024);
  };

#define QUAD(am, MQ, NQ)                                                        \
  do {                                                                          \
    SETPRIO(1);                                                                 \
    _Pragma("unroll") for (int m = 0; m < 4; ++m) {                             \
      _Pragma("unroll") for (int n = 0; n < 2; ++n) {                           \
        _Pragma("unroll") for (int ks = 0; ks < 2; ++ks) {                      \
          acc[(MQ)*4 + m][(NQ)*2 + n] = __builtin_amdgcn_mfma_f32_16x16x32_bf16(\
              am[m][ks], b[(NQ)*2 + n][ks], acc[(MQ)*4 + m][(NQ)*2 + n], 0, 0, 0);\
        }                                                                       \
      }                                                                         \
    }                                                                           \
    SETPRIO(0);                                                                 \
  } while (0)

  stageB(0, 0, 0); stageB(0, 1, 0); stageA(0, 0, 0); stageA(0, 1, 0);
  stageB(1, 0, 1); stageB(1, 1, 1);
  VMCNT4(); BAR();

  const unsigned short* Ab0 = L;
  const unsigned short* Bb0 = L + 32768;
  const unsigned short* Ab1 = L + 16384;
  const unsigned short* Bb1 = L + 49152;

  for (int it = 0; it < NI; ++it) {
    const int t_odd = 2 * it + 1, t_e2 = 2 * it + 2, t_o3 = 2 * it + 3;
    const bool s2 = t_e2 < NT, s3 = t_o3 < NT, lastit = (it == NI - 1);
    // p0
    ldA(a0, Ab0, 0); ldB01(Bb0);
    stageA(1, 0, t_odd);
    BAR(); QUAD(a0, 0, 0); BAR();
    // p1
    ldB23(Bb0);
    stageA(1, 1, t_odd);
    BAR(); QUAD(a0, 0, 1); BAR();
    // p2
    ldA(a1, Ab0, 4);
    if (s2) stageB(0, 0, t_e2);
    BAR(); QUAD(a1, 1, 0); BAR();
    // p3
    if (s2) stageB(0, 1, t_e2);
    if (lastit) { VMCNT0(); } else { VMCNT4(); }
    BAR(); QUAD(a1, 1, 1); BAR();
    // p4
    ldA(a0, Ab1, 0); ldB01(Bb1);
    if (s2) stageA(0, 0, t_e2);
    BAR(); QUAD(a0, 0, 0); BAR();
    // p5
    ldB23(Bb1);
    if (s2) stageA(0, 1, t_e2);
    BAR(); QUAD(a0, 0, 1); BAR();
    // p6
    ldA(a1, Ab1, 4);
    if (s3) stageB(1, 0, t_o3);
    BAR(); QUAD(a1, 1, 0); BAR();
    // p7
    if (s3) stageB(1, 1, t_o3);
    if (!lastit) { VMCNT4(); }
    BAR(); QUAD(a1, 1, 1); BAR();
  }
#undef QUAD

  const int rb = m0 + wm * 128 + lg * 4;
  const int cb = n0 + wn * 64 + lrow;
  #pragma unroll
  for (int m = 0; m < 8; ++m)
    #pragma unroll
    for (int n = 0; n < 4; ++n)
      #pragma unroll
      for (int r = 0; r < 4; ++r) {
        size_t idx = (size_t)(rb + m * 16 + r) * N + (cb + n * 16);
        if constexpr (sizeof(OutT) == 2) C[idx] = (OutT)f2b(acc[m][n][r]);
        else                              C[idx] = acc[m][n][r];
      }
}

// ---------------- RoPE + layout: qkv (BS,6144) -> Qr(B,H,S,HD), Kr(B,HKV,S,HD) ----------------
__global__ void rope_kernel(const unsigned short* __restrict__ qkv,
                            const float* __restrict__ rope_cos,
                            const float* __restrict__ rope_sin,
                            unsigned short* __restrict__ Qr,
                            unsigned short* __restrict__ Kr) {
  int bs = blockIdx.x;
  int b = bs >> 10, s = bs & 1023;
  int tid = threadIdx.x;
  __shared__ float cs[64], sn[64];
  if (tid < 64) cs[tid] = rope_cos[s * 64 + tid];
  else if (tid < 128) sn[tid - 64] = rope_sin[s * 64 + (tid - 64)];
  __syncthreads();
  const unsigned short* row = qkv + (size_t)bs * NQKV_;
  for (int p = tid; p < 2048; p += 256) {
    int h = p >> 6, i = p & 63;
    uint32_t xx = *(const uint32_t*)(row + h * 128 + 2 * i);
    float x0 = b2f((unsigned short)(xx & 0xffffu));
    float x1 = b2f((unsigned short)(xx >> 16));
    float c = cs[i], d = sn[i];
    uint32_t oo = (uint32_t)f2b(x0 * c - x1 * d) | ((uint32_t)f2b(x0 * d + x1 * c) << 16);
    size_t o = ((size_t)(b * H_ + h) * S_ + s) * HD_ + 2 * i;
    *(uint32_t*)(Qr + o) = oo;
  }
  for (int p = tid; p < 512; p += 256) {
    int hk = p >> 6, i = p & 63;
    uint32_t xx = *(const uint32_t*)(row + H_ * HD_ + hk * 128 + 2 * i);
    float x0 = b2f((unsigned short)(xx & 0xffffu));
    float x1 = b2f((unsigned short)(xx >> 16));
    float c = cs[i], d = sn[i];
    uint32_t oo = (uint32_t)f2b(x0 * c - x1 * d) | ((uint32_t)f2b(x0 * d + x1 * c) << 16);
    size_t o = ((size_t)(b * HKV_ + hk) * S_ + s) * HD_ + 2 * i;
    *(uint32_t*)(Kr + o) = oo;
  }
}

// ---------------- V transpose: qkv V-part (s,d) -> Vt (B,HKV,HD,S) ----------------
__global__ void vtrans_kernel(const unsigned short* __restrict__ qkv,
                              unsigned short* __restrict__ Vt) {
  __shared__ unsigned short tile[32][33];
  int bh = blockIdx.z;
  int b = bh >> 3, hk = bh & 7;
  int s0 = blockIdx.x * 32, d0 = blockIdx.y * 32;
  int tx = threadIdx.x & 31, ty = threadIdx.x >> 5;
  #pragma unroll
  for (int j = 0; j < 4; ++j) {
    int r = ty * 4 + j;
    tile[r][tx] = qkv[(size_t)(b * S_ + s0 + r) * NQKV_ + (H_ + HKV_) * HD_ + hk * 128 + d0 + tx];
  }
  __syncthreads();
  #pragma unroll
  for (int j = 0; j < 4; ++j) {
    int d = ty * 4 + j;
    Vt[((size_t)bh * HD_ + d0 + d) * S_ + s0 + tx] = tile[tx][d];
  }
}

// ---------------- Flash attention v2: swapped-operand, in-register softmax ----------------
// grid (S/128, B*H), 256 thr = 4 warps x 32 q-rows. KVBLK=64, 32x32x16 MFMA.
// S^T = mfma(K, Q): lane owns q = lane&31; softmax state scalar per lane.
// P repack: cvt_pk pairs + shfl_xor(32) -> B-operand of PV.
// PV: O^T = mfma(V^T, P^T): lane holds O^T[d = crow+db*32][q = lane&31].
// LDS chunked layouts: Ks8[hc8][krow][8], Vs8[kc8][d][8] -> conflict-free b128,
// linear global_load_lds dests (rule #21: no swizzle either side).
__global__ __launch_bounds__(256, 2) void attn2_kernel(
    const unsigned short* __restrict__ Qr,   // (B,H,S,HD)
    const unsigned short* __restrict__ Kr,   // (B,HKV,S,HD)
    const unsigned short* __restrict__ Vt,   // (B,HKV,HD,S)
    unsigned short* __restrict__ Oo) {       // (B,S,H*HD)
  __shared__ unsigned short Ks8[2][16 * 64 * 8];  // [hd-chunk][krow][8]  16 KB each
  __shared__ unsigned short Vs8[2][8 * 128 * 8];  // [k-chunk][d][8]      16 KB each
  const int qt = blockIdx.x, bh = blockIdx.y;
  const int b = bh >> 5, h = bh & 31, hk = h >> 2;
  const int tid = threadIdx.x, lane = tid & 63, w = tid >> 6;
  const int l31 = lane & 31, hi = lane >> 5;
  const int q0w = qt * 128 + w * 32;
  const int q = q0w + l31;

  // Q fragments: lane holds Q[q][cs*16 + hi*8 .. +7] for cs=0..7 (B-operand)
  const unsigned short* Qb = Qr + ((size_t)(b * H_ + h) * S_ + q) * HD_;
  bf16x8 qf[8];
  #pragma unroll
  for (int cs = 0; cs < 8; ++cs)
    qf[cs] = *(const bf16x8*)(Qb + cs * 16 + hi * 8);

  f32x16 o[4];
  #pragma unroll
  for (int db = 0; db < 4; ++db) o[db] = (f32x16)0.0f;
  float mrun = -1.0e30f, lrun = 0.0f;

  const unsigned short* Kb0 = Kr + (size_t)(b * HKV_ + hk) * S_ * HD_;
  const unsigned short* Vb0 = Vt + (size_t)(b * HKV_ + hk) * HD_ * S_;

  auto stage = [&](int bb, int kt) {
    const int k0s = kt * 64;
    #pragma unroll
    for (int i = 0; i < 4; ++i) {
      int ch = tid + 256 * i;               // 0..1023, lane-consecutive per wave
      int hc8 = ch >> 6, krow = ch & 63;    // K: chunk (hd-block, k-row)
      __builtin_amdgcn_global_load_lds(GAS(Kb0 + (size_t)(k0s + krow) * HD_ + hc8 * 8),
                                       LAS(&Ks8[bb][0] + ch * 8), 16, 0, 0);
      int kc8 = ch >> 7, dd = ch & 127;     // V: chunk (k-block, d-row)
      __builtin_amdgcn_global_load_lds(GAS(Vb0 + (size_t)dd * S_ + k0s + kc8 * 8),
                                       LAS(&Vs8[bb][0] + ch * 8), 16, 0, 0);
    }
  };

  const int nt = 2 * qt + 2;
  stage(0, 0);
  __syncthreads();

  for (int kt = 0; kt < nt; ++kt) {
    if (kt + 1 < nt) stage((kt + 1) & 1, kt + 1);
    const unsigned short* Kb_ = &Ks8[kt & 1][0];
    const unsigned short* Vb_ = &Vs8[kt & 1][0];
    const int k0 = kt * 64;
    if (k0 <= q0w + 31) {  // wave-uniform causal skip
      // ---- QK^T: S^T[k][q], k split in 2 blocks of 32 ----
      f32x16 sa[2];
      sa[0] = (f32x16)0.0f; sa[1] = (f32x16)0.0f;
      #pragma unroll
      for (int kb = 0; kb < 2; ++kb) {
        SETPRIO(1);
        #pragma unroll
        for (int cs = 0; cs < 8; ++cs) {
          bf16x8 kf = *(const bf16x8*)(Kb_ + ((cs * 2 + hi) * 64 + kb * 32 + l31) * 8);
          sa[kb] = __builtin_amdgcn_mfma_f32_32x32x16_bf16(kf, qf[cs], sa[kb], 0, 0, 0);
        }
        SETPRIO(0);
      }
      // ---- causal mask (raw-S domain) ----
      if (k0 + 63 > q0w) {
        #pragma unroll
        for (int kb = 0; kb < 2; ++kb)
          #pragma unroll
          for (int r = 0; r < 16; ++r) {
            int kg = k0 + kb * 32 + (r & 3) + 8 * (r >> 2) + 4 * hi;
            if (kg > q) sa[kb][r] = -3.0e38f;
          }
      }
      // ---- online softmax: per-lane scalar state ----
      float mx[16];
      #pragma unroll
      for (int r = 0; r < 16; ++r) mx[r] = fmaxf(sa[0][r], sa[1][r]);
      #pragma unroll
      for (int s2 = 8; s2 > 0; s2 >>= 1)
        #pragma unroll
        for (int r = 0; r < 8; ++r)
          if (r < s2) mx[r] = fmaxf(mx[r], mx[r + s2]);
      float tm = fmaxf(mx[0], __shfl_xor(mx[0], 32, 64));
      float nm = fmaxf(mrun, tm);
      float alpha = __builtin_amdgcn_exp2f((mrun - nm) * C1);
      float nmc = nm * C1;
      #pragma unroll
      for (int kb = 0; kb < 2; ++kb)
        #pragma unroll
        for (int r = 0; r < 16; ++r)
          sa[kb][r] = __builtin_amdgcn_exp2f(__builtin_fmaf(sa[kb][r], C1, -nmc));
      float sm[16];
      #pragma unroll
      for (int r = 0; r < 16; ++r) sm[r] = sa[0][r] + sa[1][r];
      #pragma unroll
      for (int s2 = 8; s2 > 0; s2 >>= 1)
        #pragma unroll
        for (int r = 0; r < 8; ++r)
          if (r < s2) sm[r] += sm[r + s2];
      float rs = sm[0] + __shfl_xor(sm[0], 32, 64);
      lrun = lrun * alpha + rs;
      mrun = nm;
      #pragma unroll
      for (int db = 0; db < 4; ++db) o[db] = o[db] * alpha;
      // ---- P repack (cvt_pk + shfl_xor) and PV ----
      #pragma unroll
      for (int ks = 0; ks < 4; ++ks) {
        const int kb = ks >> 1, r0 = (ks & 1) * 8;
        uint32_t t0 = cvt_pk_bf16(sa[kb][r0 + 0], sa[kb][r0 + 1]);
        uint32_t t1 = cvt_pk_bf16(sa[kb][r0 + 2], sa[kb][r0 + 3]);
        uint32_t u0 = cvt_pk_bf16(sa[kb][r0 + 4], sa[kb][r0 + 5]);
        uint32_t u1 = cvt_pk_bf16(sa[kb][r0 + 6], sa[kb][r0 + 7]);
        uint32_t sxt0 = __shfl_xor(t0, 32, 64), sxt1 = __shfl_xor(t1, 32, 64);
        uint32_t sxu0 = __shfl_xor(u0, 32, 64), sxu1 = __shfl_xor(u1, 32, 64);
        union { uint32_t u[4]; bf16x8 v; } pw;
        pw.u[0] = hi ? sxu0 : t0;
        pw.u[1] = hi ? sxu1 : t1;
        pw.u[2] = hi ? u0 : sxt0;
        pw.u[3] = hi ? u1 : sxt1;
        SETPRIO(1);
        #pragma unroll
        for (int db = 0; db < 4; ++db) {
          bf16x8 vf = *(const bf16x8*)(Vb_ + ((ks * 2 + hi) * 128 + db * 32 + l31) * 8);
          o[db] = __builtin_amdgcn_mfma_f32_32x32x16_bf16(vf, pw.v, o[db], 0, 0, 0);
        }
        SETPRIO(0);
      }
    }
    __syncthreads();
  }

  // ---- epilogue: O^T/lrun -> Oo[b,q,h*128+d]; d = db*32 + 8*m4 + 4*hi + j ----
  const float inv = 1.0f / lrun;
  unsigned short* orow = Oo + ((size_t)(b * S_ + q)) * (H_ * HD_) + h * HD_;
  #pragma unroll
  for (int db = 0; db < 4; ++db)
    #pragma unroll
    for (int m4 = 0; m4 < 4; ++m4) {
      ushort4 s4;
      s4.x = f2b(o[db][m4 * 4 + 0] * inv);
      s4.y = f2b(o[db][m4 * 4 + 1] * inv);
      s4.z = f2b(o[db][m4 * 4 + 2] * inv);
      s4.w = f2b(o[db][m4 * 4 + 3] * inv);
      *(ushort4*)(orow + db * 32 + m4 * 8 + hi * 4) = s4;
    }
}

// ---------------- launcher ----------------
// Workspace layout (128 MB, regions reused):
//   [0,32MB)   seq_bf16            -> later Qr
//   [32,80MB)  WqkvT (6144x4096)   -> later Kr(32..40), Vt(40..48), attn_out(48..80)
//   [80,128MB) qkv (4096x6144)     -> later WoT(80..112)
extern "C" void kernel_launch(void* const* d_in, const int* in_sizes, int n_in,
                              void* d_out, int out_size, void* d_ws, size_t ws_size,
                              hipStream_t stream) {
  const float* seq = (const float*)d_in[0];
  const float* Wq  = (const float*)d_in[1];
  const float* Wk  = (const float*)d_in[2];
  const float* Wv  = (const float*)d_in[3];
  const float* Wo  = (const float*)d_in[4];
  const float* rc  = (const float*)d_in[5];
  const float* rsn = (const float*)d_in[6];
  float* out = (float*)d_out;
  char* ws = (char*)d_ws;

  unsigned short* seqb  = (unsigned short*)(ws);
  unsigned short* WqkvT = (unsigned short*)(ws + (32ull << 20));
  unsigned short* qkv   = (unsigned short*)(ws + (80ull << 20));
  unsigned short* Qr    = (unsigned short*)(ws);
  unsigned short* Kr    = (unsigned short*)(ws + (32ull << 20));
  unsigned short* Vt    = (unsigned short*)(ws + (40ull << 20));
  unsigned short* attn  = (unsigned short*)(ws + (48ull << 20));
  unsigned short* WoT   = (unsigned short*)(ws + (80ull << 20));

  cvt_bf16_kernel<<<2048, 256, 0, stream>>>(seq, seqb, BS_ * D_ / 4);
  transpose_cvt_kernel<<<dim3(128, 128), 256, 0, stream>>>(Wq, WqkvT, D_, H_ * HD_);
  transpose_cvt_kernel<<<dim3(32, 128), 256, 0, stream>>>(
      Wk, WqkvT + (size_t)H_ * HD_ * D_, D_, HKV_ * HD_);
  transpose_cvt_kernel<<<dim3(32, 128), 256, 0, stream>>>(
      Wv, WqkvT + (size_t)(H_ + HKV_) * HD_ * D_, D_, HKV_ * HD_);
  gemm256_kernel<unsigned short><<<dim3((BS_ / 256) * (NQKV_ / 256)), 512, 0, stream>>>(
      seqb, WqkvT, qkv, BS_, NQKV_, D_);
  rope_kernel<<<BS_, 256, 0, stream>>>(qkv, rc, rsn, Qr, Kr);
  vtrans_kernel<<<dim3(32, 4, 32), 256, 0, stream>>>(qkv, Vt);
  transpose_cvt_kernel<<<dim3(128, 128), 256, 0, stream>>>(Wo, WoT, H_ * HD_, D_);
  attn2_kernel<<<dim3(S_ / 128, B_ * H_), 256, 0, stream>>>(Qr, Kr, Vt, attn);
  gemm256_kernel<float><<<dim3((BS_ / 256) * (D_ / 256)), 512, 0, stream>>>(
      attn, WoT, out, BS_, D_, D_);
}

// Round 6
// 673.763 us; speedup vs baseline: 1.5014x; 1.0375x over previous
//
#include <hip/hip_runtime.h>
#include <hip/hip_bf16.h>
#include <stdint.h>

#define DEVI __device__ __forceinline__

typedef __attribute__((ext_vector_type(8))) short bf16x8;
typedef __attribute__((ext_vector_type(4))) float f32x4;
typedef __attribute__((ext_vector_type(16))) float f32x16;

constexpr int B_ = 4, S_ = 1024, D_ = 4096, H_ = 32, HKV_ = 8, HD_ = 128;
constexpr int BS_ = B_ * S_;                 // 4096 tokens
constexpr int NQKV_ = (H_ + 2 * HKV_) * HD_; // 6144
constexpr float ATT_SCALE = 0.08838834764831845f; // 1/sqrt(128)
constexpr float LOG2E = 1.4426950408889634f;
constexpr float C1 = ATT_SCALE * LOG2E;

DEVI unsigned short f2b(float f) {
  union { float f; uint32_t u; } x; x.f = f;
  uint32_t r = x.u + 0x7fffu + ((x.u >> 16) & 1u);
  return (unsigned short)(r >> 16);
}
DEVI float b2f(unsigned short b) {
  union { uint32_t u; float f; } x; x.u = ((uint32_t)b) << 16;
  return x.f;
}
DEVI uint32_t cvt_pk_bf16(float lo, float hi_) {
  uint32_t r;
  asm("v_cvt_pk_bf16_f32 %0, %1, %2" : "=v"(r) : "v"(lo), "v"(hi_));
  return r;
}

#define GAS(p) ((__attribute__((address_space(1))) void*)(p))
#define LAS(p) ((__attribute__((address_space(3))) void*)(p))
#define BAR() __builtin_amdgcn_s_barrier()
#define SETPRIO(x) __builtin_amdgcn_s_setprio(x)
#define VMCNT4() do { asm volatile("s_waitcnt vmcnt(4)" ::: "memory"); __builtin_amdgcn_sched_barrier(0); } while (0)
#define VMCNT0() do { asm volatile("s_waitcnt vmcnt(0)" ::: "memory"); __builtin_amdgcn_sched_barrier(0); } while (0)

// ---------------- fp32 -> bf16 elementwise convert (vectorized) ----------------
__global__ void cvt_bf16_kernel(const float* __restrict__ src,
                                unsigned short* __restrict__ dst, int n4) {
  int i = blockIdx.x * blockDim.x + threadIdx.x;
  int stride = gridDim.x * blockDim.x;
  for (; i < n4; i += stride) {
    float4 v = ((const float4*)src)[i];
    ushort4 o;
    o.x = f2b(v.x); o.y = f2b(v.y); o.z = f2b(v.z); o.w = f2b(v.w);
    ((ushort4*)dst)[i] = o;
  }
}

// ---------------- fp32 (R x C) -> bf16 (C x R) tiled transpose-convert ----------------
__global__ void transpose_cvt_kernel(const float* __restrict__ src,
                                     unsigned short* __restrict__ dst,
                                     int R, int C) {
  __shared__ unsigned short tile[32][33];
  int tx = threadIdx.x & 31, ty = threadIdx.x >> 5; // 32 x 8
  int r0 = blockIdx.y * 32, c0 = blockIdx.x * 32;
  #pragma unroll
  for (int j = 0; j < 4; ++j) {
    int r = ty * 4 + j;
    tile[r][tx] = f2b(src[(size_t)(r0 + r) * C + (c0 + tx)]);
  }
  __syncthreads();
  #pragma unroll
  for (int j = 0; j < 4; ++j) {
    int c = ty * 4 + j;
    dst[(size_t)(c0 + c) * R + (r0 + tx)] = tile[tx][c];
  }
}

// ---------------- 256x256 8-phase GEMM: C(MxN)=A(MxK)*Bt(NxK)^T ----------------
template <typename OutT>
__global__ __launch_bounds__(512, 2) void gemm256_kernel(
    const unsigned short* __restrict__ A,
    const unsigned short* __restrict__ Bt,
    OutT* __restrict__ C, int M, int N, int K) {
  __shared__ unsigned short L[4 * 16384];  // 128 KiB
  const int tid = threadIdx.x, lane = tid & 63, w = tid >> 6;
  const int lrow = lane & 15, lg = lane >> 4;
  const int wm = w >> 2, wn = w & 3;

  const int nbx = N >> 8;
  const int nblk = gridDim.x;
  int id = blockIdx.x;
  int swz = ((nblk & 7) == 0) ? ((id & 7) * (nblk >> 3) + (id >> 3)) : id;
  const int m0 = (swz / nbx) << 8, n0 = (swz % nbx) << 8;

  const int NT = K >> 6, NI = NT >> 1;

  const int sr = lane >> 3, sc = lane & 7;
  const int scx = (sc ^ sr) * 8;  // swizzled source column (elements)

  int aoff[2], boff[2];
  #pragma unroll
  for (int ks = 0; ks < 2; ++ks) {
    int cp = ((ks * 4 + lg) ^ (lrow & 7)) * 8;
    aoff[ks] = wm * 8192 + lrow * 64 + cp;
    boff[ks] = wn * 4096 + lrow * 64 + cp;
  }

  f32x4 acc[8][4];
  #pragma unroll
  for (int m = 0; m < 8; ++m)
    #pragma unroll
    for (int n = 0; n < 4; ++n) acc[m][n] = (f32x4)0.0f;

  auto stageA = [&](int buf, int half, int t) {
    unsigned short* base = L + buf * 16384 + half * 8192;
    const unsigned short* src = A + (size_t)(m0 + half * 128) * K + (size_t)t * 64;
    #pragma unroll
    for (int j = 0; j < 2; ++j) {
      int rl = (w * 2 + j) * 8 + sr;
      __builtin_amdgcn_global_load_lds(GAS(src + (size_t)rl * K + scx),
                                       LAS(base + (w * 2 + j) * 512), 16, 0, 0);
    }
  };
  auto stageB = [&](int buf, int half, int t) {
    unsigned short* base = L + 32768 + buf * 16384 + half * 8192;
    const unsigned short* src = Bt + (size_t)(n0 + half * 128) * K + (size_t)t * 64;
    #pragma unroll
    for (int j = 0; j < 2; ++j) {
      int rl = (w * 2 + j) * 8 + sr;
      __builtin_amdgcn_global_load_lds(GAS(src + (size_t)rl * K + scx),
                                       LAS(base + (w * 2 + j) * 512), 16, 0, 0);
    }
  };

  bf16x8 a0[4][2], a1[4][2], b[4][2];
  auto ldA = [&](bf16x8 (&dst)[4][2], const unsigned short* Ab, int mbase) {
    #pragma unroll
    for (int m = 0; m < 4; ++m)
      #pragma unroll
      for (int ks = 0; ks < 2; ++ks)
        dst[m][ks] = *(const bf16x8*)(Ab + aoff[ks] + (mbase + m) * 1024);
  };
  auto ldB01 = [&](const unsigned short* Bb) {
    #pragma unroll
    for (int n = 0; n < 2; ++n)
      #pragma unroll
      for (int ks = 0; ks < 2; ++ks)
        b[n][ks] = *(const bf16x8*)(Bb + boff[ks] + n * 1024);
  };
  auto ldB23 = [&](const unsigned short* Bb) {
    #pragma unroll
    for (int n = 0; n < 2; ++n)
      #pragma unroll
      for (int ks = 0; ks < 2; ++ks)
        b[2 + n][ks] = *(const bf16x8*)(Bb + boff[ks] + (2 + n) * 1024);
  };

#define QUAD(am, MQ, NQ)                                                        \
  do {                                                                          \
    SETPRIO(1);                                                                 \
    _Pragma("unroll") for (int m = 0; m < 4; ++m) {                             \
      _Pragma("unroll") for (int n = 0; n < 2; ++n) {                           \
        _Pragma("unroll") for (int ks = 0; ks < 2; ++ks) {                      \
          acc[(MQ)*4 + m][(NQ)*2 + n] = __builtin_amdgcn_mfma_f32_16x16x32_bf16(\
              am[m][ks], b[(NQ)*2 + n][ks], acc[(MQ)*4 + m][(NQ)*2 + n], 0, 0, 0);\
        }                                                                       \
      }                                                                         \
    }                                                                           \
    SETPRIO(0);                                                                 \
  } while (0)

  stageB(0, 0, 0); stageB(0, 1, 0); stageA(0, 0, 0); stageA(0, 1, 0);
  stageB(1, 0, 1); stageB(1, 1, 1);
  VMCNT4(); BAR();

  const unsigned short* Ab0 = L;
  const unsigned short* Bb0 = L + 32768;
  const unsigned short* Ab1 = L + 16384;
  const unsigned short* Bb1 = L + 49152;

  for (int it = 0; it < NI; ++it) {
    const int t_odd = 2 * it + 1, t_e2 = 2 * it + 2, t_o3 = 2 * it + 3;
    const bool s2 = t_e2 < NT, s3 = t_o3 < NT, lastit = (it == NI - 1);
    // p0
    ldA(a0, Ab0, 0); ldB01(Bb0);
    stageA(1, 0, t_odd);
    BAR(); QUAD(a0, 0, 0); BAR();
    // p1
    ldB23(Bb0);
    stageA(1, 1, t_odd);
    BAR(); QUAD(a0, 0, 1); BAR();
    // p2
    ldA(a1, Ab0, 4);
    if (s2) stageB(0, 0, t_e2);
    BAR(); QUAD(a1, 1, 0); BAR();
    // p3
    if (s2) stageB(0, 1, t_e2);
    if (lastit) { VMCNT0(); } else { VMCNT4(); }
    BAR(); QUAD(a1, 1, 1); BAR();
    // p4
    ldA(a0, Ab1, 0); ldB01(Bb1);
    if (s2) stageA(0, 0, t_e2);
    BAR(); QUAD(a0, 0, 0); BAR();
    // p5
    ldB23(Bb1);
    if (s2) stageA(0, 1, t_e2);
    BAR(); QUAD(a0, 0, 1); BAR();
    // p6
    ldA(a1, Ab1, 4);
    if (s3) stageB(1, 0, t_o3);
    BAR(); QUAD(a1, 1, 0); BAR();
    // p7
    if (s3) stageB(1, 1, t_o3);
    if (!lastit) { VMCNT4(); }
    BAR(); QUAD(a1, 1, 1); BAR();
  }
#undef QUAD

  const int rb = m0 + wm * 128 + lg * 4;
  const int cb = n0 + wn * 64 + lrow;
  #pragma unroll
  for (int m = 0; m < 8; ++m)
    #pragma unroll
    for (int n = 0; n < 4; ++n)
      #pragma unroll
      for (int r = 0; r < 4; ++r) {
        size_t idx = (size_t)(rb + m * 16 + r) * N + (cb + n * 16);
        if constexpr (sizeof(OutT) == 2) C[idx] = (OutT)f2b(acc[m][n][r]);
        else                              C[idx] = acc[m][n][r];
      }
}

// ---------------- RoPE + layout: qkv (BS,6144) -> Qr(B,H,S,HD), Kr(B,HKV,S,HD) ----------------
__global__ void rope_kernel(const unsigned short* __restrict__ qkv,
                            const float* __restrict__ rope_cos,
                            const float* __restrict__ rope_sin,
                            unsigned short* __restrict__ Qr,
                            unsigned short* __restrict__ Kr) {
  int bs = blockIdx.x;
  int b = bs >> 10, s = bs & 1023;
  int tid = threadIdx.x;
  __shared__ float cs[64], sn[64];
  if (tid < 64) cs[tid] = rope_cos[s * 64 + tid];
  else if (tid < 128) sn[tid - 64] = rope_sin[s * 64 + (tid - 64)];
  __syncthreads();
  const unsigned short* row = qkv + (size_t)bs * NQKV_;
  for (int p = tid; p < 2048; p += 256) {
    int h = p >> 6, i = p & 63;
    uint32_t xx = *(const uint32_t*)(row + h * 128 + 2 * i);
    float x0 = b2f((unsigned short)(xx & 0xffffu));
    float x1 = b2f((unsigned short)(xx >> 16));
    float c = cs[i], d = sn[i];
    uint32_t oo = (uint32_t)f2b(x0 * c - x1 * d) | ((uint32_t)f2b(x0 * d + x1 * c) << 16);
    size_t o = ((size_t)(b * H_ + h) * S_ + s) * HD_ + 2 * i;
    *(uint32_t*)(Qr + o) = oo;
  }
  for (int p = tid; p < 512; p += 256) {
    int hk = p >> 6, i = p & 63;
    uint32_t xx = *(const uint32_t*)(row + H_ * HD_ + hk * 128 + 2 * i);
    float x0 = b2f((unsigned short)(xx & 0xffffu));
    float x1 = b2f((unsigned short)(xx >> 16));
    float c = cs[i], d = sn[i];
    uint32_t oo = (uint32_t)f2b(x0 * c - x1 * d) | ((uint32_t)f2b(x0 * d + x1 * c) << 16);
    size_t o = ((size_t)(b * HKV_ + hk) * S_ + s) * HD_ + 2 * i;
    *(uint32_t*)(Kr + o) = oo;
  }
}

// ---------------- V transpose: qkv V-part (s,d) -> Vt (B,HKV,HD,S) ----------------
__global__ void vtrans_kernel(const unsigned short* __restrict__ qkv,
                              unsigned short* __restrict__ Vt) {
  __shared__ unsigned short tile[32][33];
  int bh = blockIdx.z;
  int b = bh >> 3, hk = bh & 7;
  int s0 = blockIdx.x * 32, d0 = blockIdx.y * 32;
  int tx = threadIdx.x & 31, ty = threadIdx.x >> 5;
  #pragma unroll
  for (int j = 0; j < 4; ++j) {
    int r = ty * 4 + j;
    tile[r][tx] = qkv[(size_t)(b * S_ + s0 + r) * NQKV_ + (H_ + HKV_) * HD_ + hk * 128 + d0 + tx];
  }
  __syncthreads();
  #pragma unroll
  for (int j = 0; j < 4; ++j) {
    int d = ty * 4 + j;
    Vt[((size_t)bh * HD_ + d0 + d) * S_ + s0 + tx] = tile[tx][d];
  }
}

// ---------------- Flash attention v3: QBLK=256, 8 waves, balanced causal pairing --------
// grid (2, B*H): block x processes q-tiles {x, 3-x} (20 KV-tile steps each -> balanced,
// 256 blocks = one round on 256 CUs). 8 waves x 32 q-rows. KVBLK=64, 32x32x16 MFMA.
// S^T = mfma(K, Q): lane owns q = lane&31; softmax state scalar per lane.
// P repack: cvt_pk pairs + shfl_xor(32) -> B-operand of PV.
// PV: O^T = mfma(V^T, P^T): lane holds O^T[d][q].
// LDS chunked layouts: Ks8[hc8][krow][8], Vs8[kc8][d][8] -> conflict-free b128,
// linear global_load_lds dests (rule #21: no swizzle either side).
__global__ __launch_bounds__(512, 2) void attn3_kernel(
    const unsigned short* __restrict__ Qr,   // (B,H,S,HD)
    const unsigned short* __restrict__ Kr,   // (B,HKV,S,HD)
    const unsigned short* __restrict__ Vt,   // (B,HKV,HD,S)
    unsigned short* __restrict__ Oo) {       // (B,S,H*HD)
  __shared__ unsigned short Ks8[2][16 * 64 * 8];  // [hd-chunk][krow][8]  16 KB each
  __shared__ unsigned short Vs8[2][8 * 128 * 8];  // [k-chunk][d][8]      16 KB each
  const int bh = blockIdx.y;
  const int b = bh >> 5, h = bh & 31, hk = h >> 2;
  const int tid = threadIdx.x, lane = tid & 63, w = tid >> 6;
  const int l31 = lane & 31, hi = lane >> 5;

  const unsigned short* Kb0 = Kr + (size_t)(b * HKV_ + hk) * S_ * HD_;
  const unsigned short* Vb0 = Vt + (size_t)(b * HKV_ + hk) * HD_ * S_;

  auto stage = [&](int bb, int kt) {
    const int k0s = kt * 64;
    #pragma unroll
    for (int i = 0; i < 2; ++i) {
      int ch = tid + 512 * i;               // 0..1023 chunk id
      int hc8 = ch >> 6, krow = ch & 63;    // K: chunk (hd-block, k-row)
      __builtin_amdgcn_global_load_lds(GAS(Kb0 + (size_t)(k0s + krow) * HD_ + hc8 * 8),
                                       LAS(&Ks8[bb][0] + ch * 8), 16, 0, 0);
      int kc8 = ch >> 7, dd = ch & 127;     // V: chunk (k-block, d-row)
      __builtin_amdgcn_global_load_lds(GAS(Vb0 + (size_t)dd * S_ + k0s + kc8 * 8),
                                       LAS(&Vs8[bb][0] + ch * 8), 16, 0, 0);
    }
  };

  #pragma unroll 1
  for (int pp = 0; pp < 2; ++pp) {
    const int qtile = pp ? (3 - blockIdx.x) : blockIdx.x;
    const int q0w = qtile * 256 + w * 32;
    const int q = q0w + l31;

    // Q fragments: lane holds Q[q][cs*16 + hi*8 .. +7] for cs=0..7 (B-operand)
    const unsigned short* Qb = Qr + ((size_t)(b * H_ + h) * S_ + q) * HD_;
    bf16x8 qf[8];
    #pragma unroll
    for (int cs = 0; cs < 8; ++cs)
      qf[cs] = *(const bf16x8*)(Qb + cs * 16 + hi * 8);

    f32x16 o[4];
    #pragma unroll
    for (int db = 0; db < 4; ++db) o[db] = (f32x16)0.0f;
    float mrun = -1.0e30f, lrun = 0.0f;

    const int nt = (qtile + 1) * 4;
    stage(0, 0);
    __syncthreads();

    for (int kt = 0; kt < nt; ++kt) {
      if (kt + 1 < nt) stage((kt + 1) & 1, kt + 1);
      const unsigned short* Kb_ = &Ks8[kt & 1][0];
      const unsigned short* Vb_ = &Vs8[kt & 1][0];
      const int k0 = kt * 64;
      if (k0 <= q0w + 31) {  // wave-uniform causal skip
        // ---- QK^T: S^T[k][q], k split in 2 blocks of 32 ----
        f32x16 sa[2];
        sa[0] = (f32x16)0.0f; sa[1] = (f32x16)0.0f;
        #pragma unroll
        for (int kb = 0; kb < 2; ++kb) {
          SETPRIO(1);
          #pragma unroll
          for (int cs = 0; cs < 8; ++cs) {
            bf16x8 kf = *(const bf16x8*)(Kb_ + ((cs * 2 + hi) * 64 + kb * 32 + l31) * 8);
            sa[kb] = __builtin_amdgcn_mfma_f32_32x32x16_bf16(kf, qf[cs], sa[kb], 0, 0, 0);
          }
          SETPRIO(0);
        }
        // ---- causal mask (raw-S domain) ----
        if (k0 + 63 > q0w) {
          #pragma unroll
          for (int kb = 0; kb < 2; ++kb)
            #pragma unroll
            for (int r = 0; r < 16; ++r) {
              int kg = k0 + kb * 32 + (r & 3) + 8 * (r >> 2) + 4 * hi;
              if (kg > q) sa[kb][r] = -3.0e38f;
            }
        }
        // ---- online softmax: per-lane scalar state ----
        float mx[16];
        #pragma unroll
        for (int r = 0; r < 16; ++r) mx[r] = fmaxf(sa[0][r], sa[1][r]);
        #pragma unroll
        for (int s2 = 8; s2 > 0; s2 >>= 1)
          #pragma unroll
          for (int r = 0; r < 8; ++r)
            if (r < s2) mx[r] = fmaxf(mx[r], mx[r + s2]);
        float tm = fmaxf(mx[0], __shfl_xor(mx[0], 32, 64));
        float nm = fmaxf(mrun, tm);
        float alpha = __builtin_amdgcn_exp2f((mrun - nm) * C1);
        float nmc = nm * C1;
        #pragma unroll
        for (int kb = 0; kb < 2; ++kb)
          #pragma unroll
          for (int r = 0; r < 16; ++r)
            sa[kb][r] = __builtin_amdgcn_exp2f(__builtin_fmaf(sa[kb][r], C1, -nmc));
        float sm[16];
        #pragma unroll
        for (int r = 0; r < 16; ++r) sm[r] = sa[0][r] + sa[1][r];
        #pragma unroll
        for (int s2 = 8; s2 > 0; s2 >>= 1)
          #pragma unroll
          for (int r = 0; r < 8; ++r)
            if (r < s2) sm[r] += sm[r + s2];
        float rs = sm[0] + __shfl_xor(sm[0], 32, 64);
        lrun = lrun * alpha + rs;
        mrun = nm;
        #pragma unroll
        for (int db = 0; db < 4; ++db) o[db] = o[db] * alpha;
        // ---- P repack (cvt_pk + shfl_xor) and PV ----
        #pragma unroll
        for (int ks = 0; ks < 4; ++ks) {
          const int kb = ks >> 1, r0 = (ks & 1) * 8;
          uint32_t t0 = cvt_pk_bf16(sa[kb][r0 + 0], sa[kb][r0 + 1]);
          uint32_t t1 = cvt_pk_bf16(sa[kb][r0 + 2], sa[kb][r0 + 3]);
          uint32_t u0 = cvt_pk_bf16(sa[kb][r0 + 4], sa[kb][r0 + 5]);
          uint32_t u1 = cvt_pk_bf16(sa[kb][r0 + 6], sa[kb][r0 + 7]);
          uint32_t sxt0 = __shfl_xor(t0, 32, 64), sxt1 = __shfl_xor(t1, 32, 64);
          uint32_t sxu0 = __shfl_xor(u0, 32, 64), sxu1 = __shfl_xor(u1, 32, 64);
          union { uint32_t u[4]; bf16x8 v; } pw;
          pw.u[0] = hi ? sxu0 : t0;
          pw.u[1] = hi ? sxu1 : t1;
          pw.u[2] = hi ? u0 : sxt0;
          pw.u[3] = hi ? u1 : sxt1;
          SETPRIO(1);
          #pragma unroll
          for (int db = 0; db < 4; ++db) {
            bf16x8 vf = *(const bf16x8*)(Vb_ + ((ks * 2 + hi) * 128 + db * 32 + l31) * 8);
            o[db] = __builtin_amdgcn_mfma_f32_32x32x16_bf16(vf, pw.v, o[db], 0, 0, 0);
          }
          SETPRIO(0);
        }
      }
      __syncthreads();
    }

    // ---- epilogue: O^T/lrun -> Oo[b,q,h*128+d]; d = db*32 + 8*m4 + 4*hi + j ----
    const float inv = 1.0f / lrun;
    unsigned short* orow = Oo + ((size_t)(b * S_ + q)) * (H_ * HD_) + h * HD_;
    #pragma unroll
    for (int db = 0; db < 4; ++db)
      #pragma unroll
      for (int m4 = 0; m4 < 4; ++m4) {
        ushort4 s4;
        s4.x = f2b(o[db][m4 * 4 + 0] * inv);
        s4.y = f2b(o[db][m4 * 4 + 1] * inv);
        s4.z = f2b(o[db][m4 * 4 + 2] * inv);
        s4.w = f2b(o[db][m4 * 4 + 3] * inv);
        *(ushort4*)(orow + db * 32 + m4 * 8 + hi * 4) = s4;
      }
  }
}

// ---------------- launcher ----------------
// Workspace layout (128 MB, regions reused):
//   [0,32MB)   seq_bf16            -> later Qr
//   [32,80MB)  WqkvT (6144x4096)   -> later Kr(32..40), Vt(40..48), attn_out(48..80)
//   [80,128MB) qkv (4096x6144)     -> later WoT(80..112)
extern "C" void kernel_launch(void* const* d_in, const int* in_sizes, int n_in,
                              void* d_out, int out_size, void* d_ws, size_t ws_size,
                              hipStream_t stream) {
  const float* seq = (const float*)d_in[0];
  const float* Wq  = (const float*)d_in[1];
  const float* Wk  = (const float*)d_in[2];
  const float* Wv  = (const float*)d_in[3];
  const float* Wo  = (const float*)d_in[4];
  const float* rc  = (const float*)d_in[5];
  const float* rsn = (const float*)d_in[6];
  float* out = (float*)d_out;
  char* ws = (char*)d_ws;

  unsigned short* seqb  = (unsigned short*)(ws);
  unsigned short* WqkvT = (unsigned short*)(ws + (32ull << 20));
  unsigned short* qkv   = (unsigned short*)(ws + (80ull << 20));
  unsigned short* Qr    = (unsigned short*)(ws);
  unsigned short* Kr    = (unsigned short*)(ws + (32ull << 20));
  unsigned short* Vt    = (unsigned short*)(ws + (40ull << 20));
  unsigned short* attn  = (unsigned short*)(ws + (48ull << 20));
  unsigned short* WoT   = (unsigned short*)(ws + (80ull << 20));

  cvt_bf16_kernel<<<2048, 256, 0, stream>>>(seq, seqb, BS_ * D_ / 4);
  transpose_cvt_kernel<<<dim3(128, 128), 256, 0, stream>>>(Wq, WqkvT, D_, H_ * HD_);
  transpose_cvt_kernel<<<dim3(32, 128), 256, 0, stream>>>(
      Wk, WqkvT + (size_t)H_ * HD_ * D_, D_, HKV_ * HD_);
  transpose_cvt_kernel<<<dim3(32, 128), 256, 0, stream>>>(
      Wv, WqkvT + (size_t)(H_ + HKV_) * HD_ * D_, D_, HKV_ * HD_);
  gemm256_kernel<unsigned short><<<dim3((BS_ / 256) * (NQKV_ / 256)), 512, 0, stream>>>(
      seqb, WqkvT, qkv, BS_, NQKV_, D_);
  rope_kernel<<<BS_, 256, 0, stream>>>(qkv, rc, rsn, Qr, Kr);
  vtrans_kernel<<<dim3(32, 4, 32), 256, 0, stream>>>(qkv, Vt);
  transpose_cvt_kernel<<<dim3(128, 128), 256, 0, stream>>>(Wo, WoT, H_ * HD_, D_);
  attn3_kernel<<<dim3(2, B_ * H_), 512, 0, stream>>>(Qr, Kr, Vt, attn);
  gemm256_kernel<float><<<dim3((BS_ / 256) * (D_ / 256)), 512, 0, stream>>>(
      attn, WoT, out, BS_, D_, D_);
}

// Round 7
// 663.423 us; speedup vs baseline: 1.5248x; 1.0156x over previous
//
#include <hip/hip_runtime.h>
#include <hip/hip_bf16.h>
#include <stdint.h>

#define DEVI __device__ __forceinline__

typedef __attribute__((ext_vector_type(8))) short bf16x8;
typedef __attribute__((ext_vector_type(4))) float f32x4;
typedef __attribute__((ext_vector_type(16))) float f32x16;

constexpr int B_ = 4, S_ = 1024, D_ = 4096, H_ = 32, HKV_ = 8, HD_ = 128;
constexpr int BS_ = B_ * S_;                 // 4096 tokens
constexpr int NQKV_ = (H_ + 2 * HKV_) * HD_; // 6144
constexpr float ATT_SCALE = 0.08838834764831845f; // 1/sqrt(128)
constexpr float LOG2E = 1.4426950408889634f;
constexpr float C1 = ATT_SCALE * LOG2E;

DEVI unsigned short f2b(float f) {
  union { float f; uint32_t u; } x; x.f = f;
  uint32_t r = x.u + 0x7fffu + ((x.u >> 16) & 1u);
  return (unsigned short)(r >> 16);
}
DEVI float b2f(unsigned short b) {
  union { uint32_t u; float f; } x; x.u = ((uint32_t)b) << 16;
  return x.f;
}
DEVI uint32_t cvt_pk_bf16(float lo, float hi_) {
  uint32_t r;
  asm("v_cvt_pk_bf16_f32 %0, %1, %2" : "=v"(r) : "v"(lo), "v"(hi_));
  return r;
}

#define GAS(p) ((__attribute__((address_space(1))) void*)(p))
#define LAS(p) ((__attribute__((address_space(3))) void*)(p))
#define BAR() __builtin_amdgcn_s_barrier()
#define SETPRIO(x) __builtin_amdgcn_s_setprio(x)
#define VMCNT4() do { asm volatile("s_waitcnt vmcnt(4)" ::: "memory"); __builtin_amdgcn_sched_barrier(0); } while (0)
#define VMCNT0() do { asm volatile("s_waitcnt vmcnt(0)" ::: "memory"); __builtin_amdgcn_sched_barrier(0); } while (0)

// ---------------- fp32 -> bf16 elementwise convert (vectorized) ----------------
__global__ void cvt_bf16_kernel(const float* __restrict__ src,
                                unsigned short* __restrict__ dst, int n4) {
  int i = blockIdx.x * blockDim.x + threadIdx.x;
  int stride = gridDim.x * blockDim.x;
  for (; i < n4; i += stride) {
    float4 v = ((const float4*)src)[i];
    ushort4 o;
    o.x = f2b(v.x); o.y = f2b(v.y); o.z = f2b(v.z); o.w = f2b(v.w);
    ((ushort4*)dst)[i] = o;
  }
}

// ---------------- fp32 (R x C) -> bf16 (C x R) transpose-convert, vectorized ----------------
// 64x64 tile / 256 thr. float4 coalesced loads; LDS [64][72] (144B rows, 16B-aligned,
// write 2-way max = free, read min-pass); ushort8 (16B) coalesced stores.
__global__ void transpose_cvt2_kernel(const float* __restrict__ src,
                                      unsigned short* __restrict__ dst,
                                      int R, int C) {
  __shared__ unsigned short t[64][72];
  const int r0 = blockIdx.y * 64, c0 = blockIdx.x * 64;
  const int cq = (threadIdx.x & 15) * 4;   // col within tile (x4)
  const int rr = threadIdx.x >> 4;         // 0..15
  #pragma unroll
  for (int p = 0; p < 4; ++p) {
    int r = p * 16 + rr;
    float4 v = *(const float4*)(src + (size_t)(r0 + r) * C + c0 + cq);
    t[cq + 0][r] = f2b(v.x);
    t[cq + 1][r] = f2b(v.y);
    t[cq + 2][r] = f2b(v.z);
    t[cq + 3][r] = f2b(v.w);
  }
  __syncthreads();
  const int ch = threadIdx.x & 7;          // 16B chunk within out row
  #pragma unroll
  for (int p = 0; p < 2; ++p) {
    int c = p * 32 + (threadIdx.x >> 3);   // out row = src col
    *(bf16x8*)(dst + (size_t)(c0 + c) * R + r0 + ch * 8) = *(const bf16x8*)&t[c][ch * 8];
  }
}

// ---------------- 256x256 8-phase GEMM: C(MxN)=A(MxK)*Bt(NxK)^T ----------------
template <typename OutT>
__global__ __launch_bounds__(512, 2) void gemm256_kernel(
    const unsigned short* __restrict__ A,
    const unsigned short* __restrict__ Bt,
    OutT* __restrict__ C, int M, int N, int K) {
  __shared__ unsigned short L[4 * 16384];  // 128 KiB
  const int tid = threadIdx.x, lane = tid & 63, w = tid >> 6;
  const int lrow = lane & 15, lg = lane >> 4;
  const int wm = w >> 2, wn = w & 3;

  const int nbx = N >> 8;
  const int nblk = gridDim.x;
  int id = blockIdx.x;
  int swz = ((nblk & 7) == 0) ? ((id & 7) * (nblk >> 3) + (id >> 3)) : id;
  const int m0 = (swz / nbx) << 8, n0 = (swz % nbx) << 8;

  const int NT = K >> 6, NI = NT >> 1;

  const int sr = lane >> 3, sc = lane & 7;
  const int scx = (sc ^ sr) * 8;  // swizzled source column (elements)

  int aoff[2], boff[2];
  #pragma unroll
  for (int ks = 0; ks < 2; ++ks) {
    int cp = ((ks * 4 + lg) ^ (lrow & 7)) * 8;
    aoff[ks] = wm * 8192 + lrow * 64 + cp;
    boff[ks] = wn * 4096 + lrow * 64 + cp;
  }

  f32x4 acc[8][4];
  #pragma unroll
  for (int m = 0; m < 8; ++m)
    #pragma unroll
    for (int n = 0; n < 4; ++n) acc[m][n] = (f32x4)0.0f;

  auto stageA = [&](int buf, int half, int t) {
    unsigned short* base = L + buf * 16384 + half * 8192;
    const unsigned short* src = A + (size_t)(m0 + half * 128) * K + (size_t)t * 64;
    #pragma unroll
    for (int j = 0; j < 2; ++j) {
      int rl = (w * 2 + j) * 8 + sr;
      __builtin_amdgcn_global_load_lds(GAS(src + (size_t)rl * K + scx),
                                       LAS(base + (w * 2 + j) * 512), 16, 0, 0);
    }
  };
  auto stageB = [&](int buf, int half, int t) {
    unsigned short* base = L + 32768 + buf * 16384 + half * 8192;
    const unsigned short* src = Bt + (size_t)(n0 + half * 128) * K + (size_t)t * 64;
    #pragma unroll
    for (int j = 0; j < 2; ++j) {
      int rl = (w * 2 + j) * 8 + sr;
      __builtin_amdgcn_global_load_lds(GAS(src + (size_t)rl * K + scx),
                                       LAS(base + (w * 2 + j) * 512), 16, 0, 0);
    }
  };

  bf16x8 a0[4][2], a1[4][2], b[4][2];
  auto ldA = [&](bf16x8 (&dst)[4][2], const unsigned short* Ab, int mbase) {
    #pragma unroll
    for (int m = 0; m < 4; ++m)
      #pragma unroll
      for (int ks = 0; ks < 2; ++ks)
        dst[m][ks] = *(const bf16x8*)(Ab + aoff[ks] + (mbase + m) * 1024);
  };
  auto ldB01 = [&](const unsigned short* Bb) {
    #pragma unroll
    for (int n = 0; n < 2; ++n)
      #pragma unroll
      for (int ks = 0; ks < 2; ++ks)
        b[n][ks] = *(const bf16x8*)(Bb + boff[ks] + n * 1024);
  };
  auto ldB23 = [&](const unsigned short* Bb) {
    #pragma unroll
    for (int n = 0; n < 2; ++n)
      #pragma unroll
      for (int ks = 0; ks < 2; ++ks)
        b[2 + n][ks] = *(const bf16x8*)(Bb + boff[ks] + (2 + n) * 1024);
  };

#define QUAD(am, MQ, NQ)                                                        \
  do {                                                                          \
    SETPRIO(1);                                                                 \
    _Pragma("unroll") for (int m = 0; m < 4; ++m) {                             \
      _Pragma("unroll") for (int n = 0; n < 2; ++n) {                           \
        _Pragma("unroll") for (int ks = 0; ks < 2; ++ks) {                      \
          acc[(MQ)*4 + m][(NQ)*2 + n] = __builtin_amdgcn_mfma_f32_16x16x32_bf16(\
              am[m][ks], b[(NQ)*2 + n][ks], acc[(MQ)*4 + m][(NQ)*2 + n], 0, 0, 0);\
        }                                                                       \
      }                                                                         \
    }                                                                           \
    SETPRIO(0);                                                                 \
  } while (0)

  stageB(0, 0, 0); stageB(0, 1, 0); stageA(0, 0, 0); stageA(0, 1, 0);
  stageB(1, 0, 1); stageB(1, 1, 1);
  VMCNT4(); BAR();

  const unsigned short* Ab0 = L;
  const unsigned short* Bb0 = L + 32768;
  const unsigned short* Ab1 = L + 16384;
  const unsigned short* Bb1 = L + 49152;

  for (int it = 0; it < NI; ++it) {
    const int t_odd = 2 * it + 1, t_e2 = 2 * it + 2, t_o3 = 2 * it + 3;
    const bool s2 = t_e2 < NT, s3 = t_o3 < NT, lastit = (it == NI - 1);
    // p0
    ldA(a0, Ab0, 0); ldB01(Bb0);
    stageA(1, 0, t_odd);
    BAR(); QUAD(a0, 0, 0); BAR();
    // p1
    ldB23(Bb0);
    stageA(1, 1, t_odd);
    BAR(); QUAD(a0, 0, 1); BAR();
    // p2
    ldA(a1, Ab0, 4);
    if (s2) stageB(0, 0, t_e2);
    BAR(); QUAD(a1, 1, 0); BAR();
    // p3
    if (s2) stageB(0, 1, t_e2);
    if (lastit) { VMCNT0(); } else { VMCNT4(); }
    BAR(); QUAD(a1, 1, 1); BAR();
    // p4
    ldA(a0, Ab1, 0); ldB01(Bb1);
    if (s2) stageA(0, 0, t_e2);
    BAR(); QUAD(a0, 0, 0); BAR();
    // p5
    ldB23(Bb1);
    if (s2) stageA(0, 1, t_e2);
    BAR(); QUAD(a0, 0, 1); BAR();
    // p6
    ldA(a1, Ab1, 4);
    if (s3) stageB(1, 0, t_o3);
    BAR(); QUAD(a1, 1, 0); BAR();
    // p7
    if (s3) stageB(1, 1, t_o3);
    if (!lastit) { VMCNT4(); }
    BAR(); QUAD(a1, 1, 1); BAR();
  }
#undef QUAD

  const int rb = m0 + wm * 128 + lg * 4;
  const int cb = n0 + wn * 64 + lrow;
  #pragma unroll
  for (int m = 0; m < 8; ++m)
    #pragma unroll
    for (int n = 0; n < 4; ++n)
      #pragma unroll
      for (int r = 0; r < 4; ++r) {
        size_t idx = (size_t)(rb + m * 16 + r) * N + (cb + n * 16);
        if constexpr (sizeof(OutT) == 2) C[idx] = (OutT)f2b(acc[m][n][r]);
        else                              C[idx] = acc[m][n][r];
      }
}

// ---------------- RoPE (vectorized): qkv (BS,6144) -> Qr(B,H,S,HD), Kr(B,HKV,S,HD) ------
// uint4 = 4 rope pairs (16B) per load/store.
__global__ void rope_kernel(const unsigned short* __restrict__ qkv,
                            const float* __restrict__ rope_cos,
                            const float* __restrict__ rope_sin,
                            unsigned short* __restrict__ Qr,
                            unsigned short* __restrict__ Kr) {
  int bs = blockIdx.x;
  int b = bs >> 10, s = bs & 1023;
  int tid = threadIdx.x;
  __shared__ float cs[64], sn[64];
  if (tid < 64) cs[tid] = rope_cos[s * 64 + tid];
  else if (tid < 128) sn[tid - 64] = rope_sin[s * 64 + (tid - 64)];
  __syncthreads();
  const unsigned short* row = qkv + (size_t)bs * NQKV_;

  auto rope4 = [&](const unsigned short* src, unsigned short* dst, int i4) {
    uint4 xx = *(const uint4*)src;
    uint32_t oo[4];
    const uint32_t* xs = &xx.x;
    #pragma unroll
    for (int j = 0; j < 4; ++j) {
      float x0 = b2f((unsigned short)(xs[j] & 0xffffu));
      float x1 = b2f((unsigned short)(xs[j] >> 16));
      float c = cs[i4 + j], d = sn[i4 + j];
      oo[j] = (uint32_t)f2b(x0 * c - x1 * d) | ((uint32_t)f2b(x0 * d + x1 * c) << 16);
    }
    *(uint4*)dst = make_uint4(oo[0], oo[1], oo[2], oo[3]);
  };

  // Q: 2048 pairs = 2 passes x 256 thr x 4 pairs
  #pragma unroll
  for (int p = 0; p < 2; ++p) {
    int pb = p * 256 + tid;
    int h = pb >> 4, i4 = (pb & 15) * 4;
    rope4(row + h * 128 + 2 * i4,
          Qr + ((size_t)(b * H_ + h) * S_ + s) * HD_ + 2 * i4, i4);
  }
  // K: 512 pairs = 128 thr x 4 pairs
  if (tid < 128) {
    int hk = tid >> 4, i4 = (tid & 15) * 4;
    rope4(row + H_ * HD_ + hk * 128 + 2 * i4,
          Kr + ((size_t)(b * HKV_ + hk) * S_ + s) * HD_ + 2 * i4, i4);
  }
}

// ---------------- V transpose: qkv V-part (s,d) -> Vt (B,HKV,HD,S) ----------------
__global__ void vtrans_kernel(const unsigned short* __restrict__ qkv,
                              unsigned short* __restrict__ Vt) {
  __shared__ unsigned short tile[32][33];
  int bh = blockIdx.z;
  int b = bh >> 3, hk = bh & 7;
  int s0 = blockIdx.x * 32, d0 = blockIdx.y * 32;
  int tx = threadIdx.x & 31, ty = threadIdx.x >> 5;
  #pragma unroll
  for (int j = 0; j < 4; ++j) {
    int r = ty * 4 + j;
    tile[r][tx] = qkv[(size_t)(b * S_ + s0 + r) * NQKV_ + (H_ + HKV_) * HD_ + hk * 128 + d0 + tx];
  }
  __syncthreads();
  #pragma unroll
  for (int j = 0; j < 4; ++j) {
    int d = ty * 4 + j;
    Vt[((size_t)bh * HD_ + d0 + d) * S_ + s0 + tx] = tile[tx][d];
  }
}

// ---------------- Flash attention v3: QBLK=256, 8 waves, balanced causal pairing --------
__global__ __launch_bounds__(512, 2) void attn3_kernel(
    const unsigned short* __restrict__ Qr,   // (B,H,S,HD)
    const unsigned short* __restrict__ Kr,   // (B,HKV,S,HD)
    const unsigned short* __restrict__ Vt,   // (B,HKV,HD,S)
    unsigned short* __restrict__ Oo) {       // (B,S,H*HD)
  __shared__ unsigned short Ks8[2][16 * 64 * 8];  // [hd-chunk][krow][8]  16 KB each
  __shared__ unsigned short Vs8[2][8 * 128 * 8];  // [k-chunk][d][8]      16 KB each
  const int bh = blockIdx.y;
  const int b = bh >> 5, h = bh & 31, hk = h >> 2;
  const int tid = threadIdx.x, lane = tid & 63, w = tid >> 6;
  const int l31 = lane & 31, hi = lane >> 5;

  const unsigned short* Kb0 = Kr + (size_t)(b * HKV_ + hk) * S_ * HD_;
  const unsigned short* Vb0 = Vt + (size_t)(b * HKV_ + hk) * HD_ * S_;

  auto stage = [&](int bb, int kt) {
    const int k0s = kt * 64;
    #pragma unroll
    for (int i = 0; i < 2; ++i) {
      int ch = tid + 512 * i;               // 0..1023 chunk id
      int hc8 = ch >> 6, krow = ch & 63;    // K: chunk (hd-block, k-row)
      __builtin_amdgcn_global_load_lds(GAS(Kb0 + (size_t)(k0s + krow) * HD_ + hc8 * 8),
                                       LAS(&Ks8[bb][0] + ch * 8), 16, 0, 0);
      int kc8 = ch >> 7, dd = ch & 127;     // V: chunk (k-block, d-row)
      __builtin_amdgcn_global_load_lds(GAS(Vb0 + (size_t)dd * S_ + k0s + kc8 * 8),
                                       LAS(&Vs8[bb][0] + ch * 8), 16, 0, 0);
    }
  };

  #pragma unroll 1
  for (int pp = 0; pp < 2; ++pp) {
    const int qtile = pp ? (3 - blockIdx.x) : blockIdx.x;
    const int q0w = qtile * 256 + w * 32;
    const int q = q0w + l31;

    const unsigned short* Qb = Qr + ((size_t)(b * H_ + h) * S_ + q) * HD_;
    bf16x8 qf[8];
    #pragma unroll
    for (int cs = 0; cs < 8; ++cs)
      qf[cs] = *(const bf16x8*)(Qb + cs * 16 + hi * 8);

    f32x16 o[4];
    #pragma unroll
    for (int db = 0; db < 4; ++db) o[db] = (f32x16)0.0f;
    float mrun = -1.0e30f, lrun = 0.0f;

    const int nt = (qtile + 1) * 4;
    stage(0, 0);
    __syncthreads();

    for (int kt = 0; kt < nt; ++kt) {
      if (kt + 1 < nt) stage((kt + 1) & 1, kt + 1);
      const unsigned short* Kb_ = &Ks8[kt & 1][0];
      const unsigned short* Vb_ = &Vs8[kt & 1][0];
      const int k0 = kt * 64;
      if (k0 <= q0w + 31) {  // wave-uniform causal skip
        f32x16 sa[2];
        sa[0] = (f32x16)0.0f; sa[1] = (f32x16)0.0f;
        #pragma unroll
        for (int kb = 0; kb < 2; ++kb) {
          SETPRIO(1);
          #pragma unroll
          for (int cs = 0; cs < 8; ++cs) {
            bf16x8 kf = *(const bf16x8*)(Kb_ + ((cs * 2 + hi) * 64 + kb * 32 + l31) * 8);
            sa[kb] = __builtin_amdgcn_mfma_f32_32x32x16_bf16(kf, qf[cs], sa[kb], 0, 0, 0);
          }
          SETPRIO(0);
        }
        if (k0 + 63 > q0w) {
          #pragma unroll
          for (int kb = 0; kb < 2; ++kb)
            #pragma unroll
            for (int r = 0; r < 16; ++r) {
              int kg = k0 + kb * 32 + (r & 3) + 8 * (r >> 2) + 4 * hi;
              if (kg > q) sa[kb][r] = -3.0e38f;
            }
        }
        float mx[16];
        #pragma unroll
        for (int r = 0; r < 16; ++r) mx[r] = fmaxf(sa[0][r], sa[1][r]);
        #pragma unroll
        for (int s2 = 8; s2 > 0; s2 >>= 1)
          #pragma unroll
          for (int r = 0; r < 8; ++r)
            if (r < s2) mx[r] = fmaxf(mx[r], mx[r + s2]);
        float tm = fmaxf(mx[0], __shfl_xor(mx[0], 32, 64));
        float nm = fmaxf(mrun, tm);
        float alpha = __builtin_amdgcn_exp2f((mrun - nm) * C1);
        float nmc = nm * C1;
        #pragma unroll
        for (int kb = 0; kb < 2; ++kb)
          #pragma unroll
          for (int r = 0; r < 16; ++r)
            sa[kb][r] = __builtin_amdgcn_exp2f(__builtin_fmaf(sa[kb][r], C1, -nmc));
        float sm[16];
        #pragma unroll
        for (int r = 0; r < 16; ++r) sm[r] = sa[0][r] + sa[1][r];
        #pragma unroll
        for (int s2 = 8; s2 > 0; s2 >>= 1)
          #pragma unroll
          for (int r = 0; r < 8; ++r)
            if (r < s2) sm[r] += sm[r + s2];
        float rs = sm[0] + __shfl_xor(sm[0], 32, 64);
        lrun = lrun * alpha + rs;
        mrun = nm;
        #pragma unroll
        for (int db = 0; db < 4; ++db) o[db] = o[db] * alpha;
        #pragma unroll
        for (int ks = 0; ks < 4; ++ks) {
          const int kb = ks >> 1, r0 = (ks & 1) * 8;
          uint32_t t0 = cvt_pk_bf16(sa[kb][r0 + 0], sa[kb][r0 + 1]);
          uint32_t t1 = cvt_pk_bf16(sa[kb][r0 + 2], sa[kb][r0 + 3]);
          uint32_t u0 = cvt_pk_bf16(sa[kb][r0 + 4], sa[kb][r0 + 5]);
          uint32_t u1 = cvt_pk_bf16(sa[kb][r0 + 6], sa[kb][r0 + 7]);
          uint32_t sxt0 = __shfl_xor(t0, 32, 64), sxt1 = __shfl_xor(t1, 32, 64);
          uint32_t sxu0 = __shfl_xor(u0, 32, 64), sxu1 = __shfl_xor(u1, 32, 64);
          union { uint32_t u[4]; bf16x8 v; } pw;
          pw.u[0] = hi ? sxu0 : t0;
          pw.u[1] = hi ? sxu1 : t1;
          pw.u[2] = hi ? u0 : sxt0;
          pw.u[3] = hi ? u1 : sxt1;
          SETPRIO(1);
          #pragma unroll
          for (int db = 0; db < 4; ++db) {
            bf16x8 vf = *(const bf16x8*)(Vb_ + ((ks * 2 + hi) * 128 + db * 32 + l31) * 8);
            o[db] = __builtin_amdgcn_mfma_f32_32x32x16_bf16(vf, pw.v, o[db], 0, 0, 0);
          }
          SETPRIO(0);
        }
      }
      __syncthreads();
    }

    const float inv = 1.0f / lrun;
    unsigned short* orow = Oo + ((size_t)(b * S_ + q)) * (H_ * HD_) + h * HD_;
    #pragma unroll
    for (int db = 0; db < 4; ++db)
      #pragma unroll
      for (int m4 = 0; m4 < 4; ++m4) {
        ushort4 s4;
        s4.x = f2b(o[db][m4 * 4 + 0] * inv);
        s4.y = f2b(o[db][m4 * 4 + 1] * inv);
        s4.z = f2b(o[db][m4 * 4 + 2] * inv);
        s4.w = f2b(o[db][m4 * 4 + 3] * inv);
        *(ushort4*)(orow + db * 32 + m4 * 8 + hi * 4) = s4;
      }
  }
}

// ---------------- launcher ----------------
// Workspace layout (128 MB, regions reused):
//   [0,32MB)   seq_bf16            -> later Qr
//   [32,80MB)  WqkvT (6144x4096)   -> later Kr(32..40), Vt(40..48), attn_out(48..80)
//   [80,128MB) qkv (4096x6144)     -> later WoT(80..112)
extern "C" void kernel_launch(void* const* d_in, const int* in_sizes, int n_in,
                              void* d_out, int out_size, void* d_ws, size_t ws_size,
                              hipStream_t stream) {
  const float* seq = (const float*)d_in[0];
  const float* Wq  = (const float*)d_in[1];
  const float* Wk  = (const float*)d_in[2];
  const float* Wv  = (const float*)d_in[3];
  const float* Wo  = (const float*)d_in[4];
  const float* rc  = (const float*)d_in[5];
  const float* rsn = (const float*)d_in[6];
  float* out = (float*)d_out;
  char* ws = (char*)d_ws;

  unsigned short* seqb  = (unsigned short*)(ws);
  unsigned short* WqkvT = (unsigned short*)(ws + (32ull << 20));
  unsigned short* qkv   = (unsigned short*)(ws + (80ull << 20));
  unsigned short* Qr    = (unsigned short*)(ws);
  unsigned short* Kr    = (unsigned short*)(ws + (32ull << 20));
  unsigned short* Vt    = (unsigned short*)(ws + (40ull << 20));
  unsigned short* attn  = (unsigned short*)(ws + (48ull << 20));
  unsigned short* WoT   = (unsigned short*)(ws + (80ull << 20));

  cvt_bf16_kernel<<<2048, 256, 0, stream>>>(seq, seqb, BS_ * D_ / 4);
  transpose_cvt2_kernel<<<dim3(64, 64), 256, 0, stream>>>(Wq, WqkvT, D_, H_ * HD_);
  transpose_cvt2_kernel<<<dim3(16, 64), 256, 0, stream>>>(
      Wk, WqkvT + (size_t)H_ * HD_ * D_, D_, HKV_ * HD_);
  transpose_cvt2_kernel<<<dim3(16, 64), 256, 0, stream>>>(
      Wv, WqkvT + (size_t)(H_ + HKV_) * HD_ * D_, D_, HKV_ * HD_);
  gemm256_kernel<unsigned short><<<dim3((BS_ / 256) * (NQKV_ / 256)), 512, 0, stream>>>(
      seqb, WqkvT, qkv, BS_, NQKV_, D_);
  rope_kernel<<<BS_, 256, 0, stream>>>(qkv, rc, rsn, Qr, Kr);
  vtrans_kernel<<<dim3(32, 4, 32), 256, 0, stream>>>(qkv, Vt);
  transpose_cvt2_kernel<<<dim3(64, 64), 256, 0, stream>>>(Wo, WoT, H_ * HD_, D_);
  attn3_kernel<<<dim3(2, B_ * H_), 512, 0, stream>>>(Qr, Kr, Vt, attn);
  gemm256_kernel<float><<<dim3((BS_ / 256) * (D_ / 256)), 512, 0, stream>>>(
      attn, WoT, out, BS_, D_, D_);
}